// Round 7
// baseline (2786.569 us; speedup 1.0000x reference)
//
#include <hip/hip_runtime.h>
#include <hip/hip_bf16.h>

// RNNDecoder: emb -> 2-layer LSTM (seq over T=128) -> generator + log_softmax
// T=128 B=32 E=512 H=512 G=2048 V=32000
//
// R7 changes:
//  - lstm_seq exchange: tag-embedded 4B elements {bf16 h | u16 tag}. Producers
//    fire relaxed stores (no vmcnt drain, no flags, no replicas). Consumers
//    stage-with-retry validating tags (want = 2t+phase). Detection+data = one
//    fabric event; staleness safe by construction. XH0/XH1 memset per launch.
//  - gemm<1> epilogue emits per-(row, n-tile) online (max,sumexp) partials to
//    scratch (aliases dead P0t); lse_fix reduces 250 partials instead of
//    re-reading 524MB of logits for pass 1.
//
// ws layout (bytes):
//  [0)         WgBf  bf16[32000][512]   32,768,000
//  [32768000)  W0e   bf16[2048][512]     2,097,152
//  [34865152)  Wr0p  bf16[2048][1024]    4,194,304
//  [39059456)  Wr1p  bf16[2048][1024]    4,194,304
//  [43253760)  b1p   f32[2048]               8,192
//  [43261952)  bias0c f32[2048]              8,192
//  [43270144)  wcd   f32[2048]               8,192
//  [43278336)  embbf bf16[4096][512]     4,194,304
//  [47472640)  outbf bf16[4096][512]     4,194,304
//  [51666944)  P0t   f32[2048][4096]    33,554,432  (aliased by PMS f32x2[4096][250])
//  [85221376)  XH0   u32[32][512]           65,536
//  [85286912)  XH1   u32[32][512]           65,536
//  [85352448)  H0I   bf16[32][512]          32,768
//  [85385216)  FOUT  bf16[32][512]          32,768
//  [85417984)  H1I   bf16[32][512]          32,768
// total 85,450,752

typedef __attribute__((ext_vector_type(8))) short bf16x8;
typedef __attribute__((ext_vector_type(4))) float f32x4;
typedef __attribute__((ext_vector_type(2))) unsigned long long u64x2;

#define AS1 __attribute__((address_space(1)))
#define AS3 __attribute__((address_space(3)))
#define RLX __ATOMIC_RELAXED
#define AGT __HIP_MEMORY_SCOPE_AGENT

__device__ __forceinline__ unsigned short f2bf(float f) {
  unsigned int u = __builtin_bit_cast(unsigned int, f);
  u += 0x7fffu + ((u >> 16) & 1u);            // round-to-nearest-even
  return (unsigned short)(u >> 16);
}

__device__ __forceinline__ void gl16(const void* g, void* l) {
  __builtin_amdgcn_global_load_lds((const AS1 unsigned int*)g,
                                   (AS3 unsigned int*)l, 16, 0, 0);
}

__device__ __forceinline__ float sigm(float x) { return 1.0f / (1.0f + __expf(-x)); }

// both u32s of a u64 carry tag 'want' in their high 16 bits?
__device__ __forceinline__ bool chk2(unsigned long long q, unsigned want) {
  return (((unsigned)(q >> 16) & 0xffffu) == want) &&
         (((unsigned)(q >> 48) & 0xffffu) == want);
}
// pack the two low-16 payloads of a u64 into one u32
__device__ __forceinline__ unsigned pack2(unsigned long long q) {
  return ((unsigned)q & 0xffffu) | (((unsigned)(q >> 32) & 0xffffu) << 16);
}

// ---------------------------------------------------------------------------
// prep: dtype conversion + weight re-layout + initial state buffers
// ---------------------------------------------------------------------------
__global__ __launch_bounds__(256, 1) void prep_k(
    const float* __restrict__ Wg,  const float* __restrict__ Wih0,
    const float* __restrict__ Whh0,const float* __restrict__ Wih1,
    const float* __restrict__ Whh1,const float* __restrict__ bih0,
    const float* __restrict__ bhh0,const float* __restrict__ bih1,
    const float* __restrict__ bhh1,const float* __restrict__ h0,
    const float* __restrict__ pout,
    unsigned short* __restrict__ WgBf, unsigned short* __restrict__ W0e,
    unsigned short* __restrict__ Wr0p, unsigned short* __restrict__ Wr1p,
    float* __restrict__ b1p, float* __restrict__ bias0c,
    float* __restrict__ wcd, unsigned short* __restrict__ H0I,
    unsigned short* __restrict__ H1I, unsigned short* __restrict__ FOUT)
{
  const long N0 = 16384000L;           // WgBf
  const long N1 = N0 + 1048576L;       // W0e
  const long N2 = N1 + 2097152L;       // Wr0p
  const long N3 = N2 + 2097152L;       // Wr1p
  const long N4 = N3 + 2048L;          // b1p
  const long N5 = N4 + 2048L;          // bias0c
  const long N6 = N5 + 2048L;          // wcd
  const long N7 = N6 + 49152L;         // state inits (3 x 16384)
  for (long i = blockIdx.x * 256L + threadIdx.x; i < N7; i += 256L * gridDim.x) {
    if (i < N0) {
      WgBf[i] = f2bf(Wg[i]);
    } else if (i < N1) {
      long k = i - N0; int g = (int)(k >> 9); int kk = (int)(k & 511);
      W0e[k] = f2bf(Wih0[g * 1025 + kk]);
    } else if (i < N2) {
      long k = i - N1; int gp = (int)(k >> 10); int kk = (int)(k & 1023);
      int j = gp >> 2, gate = gp & 3; int g = gate * 512 + j;
      float v = (kk < 512) ? Whh0[g * 512 + kk] : Wih0[g * 1025 + 513 + (kk - 512)];
      Wr0p[k] = f2bf(v);
    } else if (i < N3) {
      long k = i - N2; int gp = (int)(k >> 10); int kk = (int)(k & 1023);
      int j = gp >> 2, gate = gp & 3; int g = gate * 512 + j;
      float v = (kk < 512) ? Wih1[g * 512 + kk] : Whh1[g * 512 + (kk - 512)];
      Wr1p[k] = f2bf(v);
    } else if (i < N4) {
      int gp = (int)(i - N3); int j = gp >> 2, gate = gp & 3; int g = gate * 512 + j;
      b1p[gp] = bih1[g] + bhh1[g];
    } else if (i < N5) {
      int g = (int)(i - N4); bias0c[g] = bih0[g] + bhh0[g];
    } else if (i < N6) {
      int g = (int)(i - N5); wcd[g] = Wih0[g * 1025 + 512];
    } else {
      long k = i - N6;                 // 0..49151
      int sub = (int)(k >> 14);        // 0=H0I, 1=H1I, 2=FOUT
      int e = (int)(k & 16383);
      int b = e >> 9, j = e & 511;
      float v = (sub == 0) ? h0[b * 512 + j]
              : (sub == 1) ? h0[16384 + b * 512 + j]
                           : pout[b * 512 + j];
      unsigned short* dst = (sub == 0) ? H0I : (sub == 1) ? H1I : FOUT;
      dst[e] = f2bf(v);
    }
  }
}

// ---------------------------------------------------------------------------
// embedding
// ---------------------------------------------------------------------------
__global__ __launch_bounds__(256, 1) void emb_k(
    const int* __restrict__ ids, const float* __restrict__ wemb,
    const float* __restrict__ semb, unsigned short* __restrict__ ebf)
{
  const int tb = blockIdx.x;
  const int id = ids[tb];
  const int sp = (id < 3) ? (id + 1) : 0;
  const float* wr = wemb + (long)id * 512;
  const float* sr = semb + sp * 512;
  for (int i = threadIdx.x; i < 512; i += 256)
    ebf[tb * 512 + i] = f2bf(wr[i] + sr[i]);
}

// ---------------------------------------------------------------------------
// GEMM: D[m][n] = sum_k A[m][k]*B[n][k]  (A [M][512] bf16, B [N][512] bf16)
// EPI==0: P0t path (permuted rows + bias + countdown term)
// EPI==1: generator: C = logits+bg, plus per-(row, n-tile) (max,sumexp)
//         partials into PMS (passed via e1)
// ---------------------------------------------------------------------------
template<int EPI>
__global__ __launch_bounds__(256, 1) void gemm_bt(
    const unsigned short* __restrict__ A,
    const unsigned short* __restrict__ B, int N,
    float* __restrict__ C,
    const float* __restrict__ e0, float* __restrict__ e1,
    const float* __restrict__ e2)
{
  __shared__ unsigned short sA[4096];
  __shared__ unsigned short sB[4096];
  __shared__ float pmw[128][2][2];
  const int tid = threadIdx.x;
  const int l = tid & 63, w = tid >> 6;
  const int nb = N >> 7;
  const int bid = blockIdx.x;
  const int bm = bid / nb, bn = bid - bm * nb;

  const int u0 = w * 128 + l;
  const int u1 = u0 + 64;
  const int r0 = u0 >> 2, c0 = (u0 & 3) ^ (r0 & 3);
  const int r1 = u1 >> 2, c1 = (u1 & 3) ^ (r1 & 3);
  const unsigned short* ga0 = A + (long)(bm * 128 + r0) * 512 + c0 * 8;
  const unsigned short* ga1 = A + (long)(bm * 128 + r1) * 512 + c1 * 8;
  const unsigned short* gb0 = B + (long)(bn * 128 + r0) * 512 + c0 * 8;
  const unsigned short* gb1 = B + (long)(bn * 128 + r1) * 512 + c1 * 8;
  unsigned short* la0 = sA + (w * 2 + 0) * 512;
  unsigned short* la1 = sA + (w * 2 + 1) * 512;
  unsigned short* lb0 = sB + (w * 2 + 0) * 512;
  unsigned short* lb1 = sB + (w * 2 + 1) * 512;

  const int fr = l & 15, fc = l >> 4;
  const int wm = w >> 1, wn = w & 1;
  int aoff[4], boff[4];
#pragma unroll
  for (int mi = 0; mi < 4; ++mi) {
    int row = wm * 64 + mi * 16 + fr;
    aoff[mi] = row * 64 + ((fc ^ (row & 3)) * 16);
  }
#pragma unroll
  for (int ni = 0; ni < 4; ++ni) {
    int row = wn * 64 + ni * 16 + fr;
    boff[ni] = row * 64 + ((fc ^ (row & 3)) * 16);
  }

  f32x4 acc[4][4];
#pragma unroll
  for (int i = 0; i < 4; ++i)
#pragma unroll
    for (int jq = 0; jq < 4; ++jq) acc[i][jq] = (f32x4){0.f, 0.f, 0.f, 0.f};

  for (int kt = 0; kt < 16; ++kt) {
    __syncthreads();
    gl16(ga0 + kt * 32, la0);
    gl16(ga1 + kt * 32, la1);
    gl16(gb0 + kt * 32, lb0);
    gl16(gb1 + kt * 32, lb1);
    asm volatile("s_waitcnt vmcnt(0)" ::: "memory");
    __syncthreads();
    bf16x8 av[4], bv[4];
#pragma unroll
    for (int mi = 0; mi < 4; ++mi)
      av[mi] = *(const bf16x8*)((const char*)sA + aoff[mi]);
#pragma unroll
    for (int ni = 0; ni < 4; ++ni)
      bv[ni] = *(const bf16x8*)((const char*)sB + boff[ni]);
#pragma unroll
    for (int mi = 0; mi < 4; ++mi)
#pragma unroll
      for (int ni = 0; ni < 4; ++ni)
        acc[mi][ni] = __builtin_amdgcn_mfma_f32_16x16x32_bf16(av[mi], bv[ni], acc[mi][ni], 0, 0, 0);
  }

  const int mbase = bm * 128 + wm * 64;
  const int nbase = bn * 128 + wn * 64;

  if (EPI == 0) {
#pragma unroll
    for (int mi = 0; mi < 4; ++mi)
#pragma unroll
      for (int ni = 0; ni < 4; ++ni) {
        const int col = nbase + ni * 16 + fr;
#pragma unroll
        for (int r = 0; r < 4; ++r) {
          const int row = mbase + mi * 16 + fc * 4 + r;
          const int gp = ((row & 511) << 2) | (row >> 9);
          float v = acc[mi][ni][r] + e0[row] + e2[col] * e1[row];
          C[(long)gp * N + col] = v;
        }
      }
  } else {
    // bias + store + row-tile stats
    float m2[4][4], s2[4][4];
#pragma unroll
    for (int mi = 0; mi < 4; ++mi)
#pragma unroll
      for (int r = 0; r < 4; ++r) { m2[mi][r] = -3.0e38f; s2[mi][r] = 0.f; }
#pragma unroll
    for (int mi = 0; mi < 4; ++mi)
#pragma unroll
      for (int ni = 0; ni < 4; ++ni) {
        const int col = nbase + ni * 16 + fr;
        const float bgc = e0[col];
#pragma unroll
        for (int r = 0; r < 4; ++r) {
          float v = acc[mi][ni][r] + bgc;
          acc[mi][ni][r] = v;
          C[(long)(mbase + mi * 16 + fc * 4 + r) * N + col] = v;
          m2[mi][r] = fmaxf(m2[mi][r], v);
        }
      }
    // max over 16 fr-lanes
#pragma unroll
    for (int mi = 0; mi < 4; ++mi)
#pragma unroll
      for (int r = 0; r < 4; ++r)
#pragma unroll
        for (int s = 1; s < 16; s <<= 1)
          m2[mi][r] = fmaxf(m2[mi][r], __shfl_xor(m2[mi][r], s));
    // sumexp against shared max
#pragma unroll
    for (int mi = 0; mi < 4; ++mi)
#pragma unroll
      for (int ni = 0; ni < 4; ++ni)
#pragma unroll
        for (int r = 0; r < 4; ++r)
          s2[mi][r] += __expf(acc[mi][ni][r] - m2[mi][r]);
#pragma unroll
    for (int mi = 0; mi < 4; ++mi)
#pragma unroll
      for (int r = 0; r < 4; ++r)
#pragma unroll
        for (int s = 1; s < 16; s <<= 1)
          s2[mi][r] += __shfl_xor(s2[mi][r], s);
    if (fr == 0) {
#pragma unroll
      for (int mi = 0; mi < 4; ++mi)
#pragma unroll
        for (int r = 0; r < 4; ++r) {
          const int rl = wm * 64 + mi * 16 + fc * 4 + r;
          pmw[rl][wn][0] = m2[mi][r];
          pmw[rl][wn][1] = s2[mi][r];
        }
    }
    __syncthreads();
    if (tid < 128) {
      float ma = pmw[tid][0][0], sa = pmw[tid][0][1];
      float mb = pmw[tid][1][0], sb = pmw[tid][1][1];
      float M = fmaxf(ma, mb);
      float S = sa * __expf(ma - M) + sb * __expf(mb - M);
      float2* PMS = (float2*)e1;
      float2 o; o.x = M; o.y = S;
      PMS[(long)(bm * 128 + tid) * nb + bn] = o;
    }
  }
}

// ---------------------------------------------------------------------------
// Persistent sequential LSTM. 32 WGs x 256 thr. WG owns gate rows
// [wg*64, wg*64+64) i.e. j in [wg*16, wg*16+16).
// Exchange: XH0/XH1 u32[32][512] = {bf16 value | u16 tag}. A(t) writes XH0
// tag 2t+1; B(t) writes XH1 tag 2t+2. Consumers stage-with-retry on tags.
// sx LDS [32 b][1024 cols] persists: half0 = h0, half1 = h1/out.
// ---------------------------------------------------------------------------
__global__ __launch_bounds__(256, 1) void lstm_seq(
    const unsigned short* __restrict__ Wr0p,
    const unsigned short* __restrict__ Wr1p,
    const float* __restrict__ P0t, const float* __restrict__ b1p,
    const float* __restrict__ c0in,
    unsigned int* __restrict__ XH0, unsigned int* __restrict__ XH1,
    const unsigned short* __restrict__ H0I, const unsigned short* __restrict__ H1I,
    const unsigned short* __restrict__ FOUT,
    unsigned short* __restrict__ outbf, float* __restrict__ outs)
{
  const int tid = threadIdx.x;
  const int wg = blockIdx.x;            // 32
  const int l = tid & 63, w = tid >> 6;
  const int fr = l & 15, fc = l >> 4;

  __shared__ unsigned short sx[32768];  // 64KB: [32 b][1024 cols], swizzled
  __shared__ float sg[32][65];
  __shared__ unsigned sh[32][16];       // packed {value|tag}
  __shared__ int sBad;

  const int b = tid & 31, jl0 = tid >> 5;       // thread owns jl0, jl0+8

  float c0r[2], c1r[2], h0k[2], h1k[2];
#pragma unroll
  for (int jq = 0; jq < 2; ++jq) {
    c0r[jq] = c0in[b * 512 + wg * 16 + jl0 + jq * 8];
    c1r[jq] = c0in[16384 + b * 512 + wg * 16 + jl0 + jq * 8];
    h0k[jq] = 0.f; h1k[jq] = 0.f;
  }

  float b1v[8];
#pragma unroll
  for (int jq = 0; jq < 2; ++jq)
#pragma unroll
    for (int g = 0; g < 4; ++g)
      b1v[jq * 4 + g] = b1p[(wg * 16 + jl0 + jq * 8) * 4 + g];

  // MFMA addressing
  const char* sxb0 = (const char*)sx + fr * 2048;          // b-rows 0-15
  const char* sxb1 = (const char*)sx + (16 + fr) * 2048;   // b-rows 16-31
  const int xr = (fr & 7) << 4;
  const int wrow = (wg * 64 + w * 16 + fr) * 1024 + fc * 8;

  // producer store lane mapping (w0/w1): lane -> (batch row, j-half)
  const int pb = l >> 1, pjh = l & 1;

// ---- tagless init stage: src bf16[32][512] -> sx half, swizzled ----
#define STAGE_INIT(srcp, half)                                                \
  do {                                                                        \
    _Pragma("unroll")                                                         \
    for (int i = 0; i < 8; ++i) {                                             \
      int u = i * 256 + tid;                                                  \
      u64x2 v = *(const u64x2*)((srcp) + u * 8);                              \
      int bb = u >> 6, j2 = (u & 63) * 16;                                    \
      *(u64x2*)((char*)sx + bb * 2048 + ((((half) * 1024) + j2) ^ ((bb & 7) << 4))) = v; \
    }                                                                         \
  } while (0)

// ---- tagged stage with retry: src u32[32][512] -> sx half ----
#define STAGE_TAG(srcp, half, want)                                           \
  do {                                                                        \
    bool wrote = false;                                                       \
    for (;;) {                                                                \
      if (tid == 0) sBad = 0;                                                 \
      __syncthreads();                                                        \
      if (!wrote) {                                                           \
        unsigned long long q[32];                                             \
        _Pragma("unroll")                                                     \
        for (int i = 0; i < 16; ++i) {                                        \
          int u = i * 256 + tid;                                              \
          q[2*i]   = __hip_atomic_load((const unsigned long long*)(srcp) + u*2,   RLX, AGT); \
          q[2*i+1] = __hip_atomic_load((const unsigned long long*)(srcp) + u*2+1, RLX, AGT); \
        }                                                                     \
        bool all = true;                                                      \
        _Pragma("unroll")                                                     \
        for (int i = 0; i < 16; ++i)                                          \
          all = all && chk2(q[2*i], (want)) && chk2(q[2*i+1], (want));        \
        if (all) {                                                            \
          _Pragma("unroll")                                                   \
          for (int i = 0; i < 16; ++i) {                                      \
            int u = i * 256 + tid;                                            \
            int bb = u >> 7, j2 = (u & 127) * 8;                              \
            unsigned long long v = (unsigned long long)pack2(q[2*i])          \
                                 | ((unsigned long long)pack2(q[2*i+1]) << 32); \
            *(unsigned long long*)((char*)sx + bb * 2048                      \
                 + ((((half) * 1024) + j2) ^ ((bb & 7) << 4))) = v;           \
          }                                                                   \
          wrote = true;                                                       \
        } else {                                                              \
          sBad = 1;                                                           \
        }                                                                     \
      }                                                                       \
      __syncthreads();                                                        \
      if (sBad == 0) break;                                                   \
    }                                                                         \
  } while (0)

// split even/odd kt accumulators: dependent chain 16 -> 8
#define MFMA_HALF(Wp, k0, e0v, o0v, e1v, o1v)                                 \
  do {                                                                        \
    _Pragma("unroll")                                                         \
    for (int kp = 0; kp < 8; ++kp) {                                          \
      int kta = (k0) + kp * 2, ktb = kta + 1;                                 \
      bf16x8 bva = *(const bf16x8*)((Wp) + wrow + kta * 32);                  \
      bf16x8 x0a = *(const bf16x8*)(sxb0 + ((kta * 64 + fc * 16) ^ xr));      \
      bf16x8 x1a = *(const bf16x8*)(sxb1 + ((kta * 64 + fc * 16) ^ xr));      \
      e0v = __builtin_amdgcn_mfma_f32_16x16x32_bf16(x0a, bva, e0v, 0, 0, 0);  \
      e1v = __builtin_amdgcn_mfma_f32_16x16x32_bf16(x1a, bva, e1v, 0, 0, 0);  \
      bf16x8 bvb = *(const bf16x8*)((Wp) + wrow + ktb * 32);                  \
      bf16x8 x0b = *(const bf16x8*)(sxb0 + ((ktb * 64 + fc * 16) ^ xr));      \
      bf16x8 x1b = *(const bf16x8*)(sxb1 + ((ktb * 64 + fc * 16) ^ xr));      \
      o0v = __builtin_amdgcn_mfma_f32_16x16x32_bf16(x0b, bvb, o0v, 0, 0, 0);  \
      o1v = __builtin_amdgcn_mfma_f32_16x16x32_bf16(x1b, bvb, o1v, 0, 0, 0);  \
    }                                                                         \
  } while (0)

  // ---- pre-loop: stage h0 init into half0 ----
  STAGE_INIT(H0I, 0);
  __syncthreads();

  for (int t = 0; t < 128; ++t) {
    // ================= phase A: layer 0 =================
    float p0v[8];
#pragma unroll
    for (int jq = 0; jq < 2; ++jq)
#pragma unroll
      for (int g = 0; g < 4; ++g)
        p0v[jq * 4 + g] =
            P0t[(long)((wg * 16 + jl0 + jq * 8) * 4 + g) * 4096 + t * 32 + b];

    f32x4 aA0e = (f32x4){0.f,0.f,0.f,0.f}, aA0o = (f32x4){0.f,0.f,0.f,0.f};
    f32x4 aA1e = (f32x4){0.f,0.f,0.f,0.f}, aA1o = (f32x4){0.f,0.f,0.f,0.f};
    MFMA_HALF(Wr0p, 0, aA0e, aA0o, aA1e, aA1o);   // resident h0(t-1), half0

    if (t == 0) {
      STAGE_INIT(FOUT, 1);
      __syncthreads();
    } else {
      STAGE_TAG(XH1, 1, (unsigned)(2 * t));       // h1(t-1)/out(t-1)
    }
    MFMA_HALF(Wr0p, 16, aA0e, aA0o, aA1e, aA1o);  // fresh half1
    {
      f32x4 s0 = aA0e + aA0o, s1 = aA1e + aA1o;
#pragma unroll
      for (int r = 0; r < 4; ++r) {
        sg[fc * 4 + r][w * 16 + fr] = s0[r];
        sg[16 + fc * 4 + r][w * 16 + fr] = s1[r];
      }
    }
    __syncthreads();
    {
      const unsigned tA = (unsigned)(2 * t + 1) << 16;
#pragma unroll
      for (int jq = 0; jq < 2; ++jq) {
        const int jl = jl0 + jq * 8;
        float gi = sg[b][jl * 4 + 0] + p0v[jq * 4 + 0];
        float gf = sg[b][jl * 4 + 1] + p0v[jq * 4 + 1];
        float gg = sg[b][jl * 4 + 2] + p0v[jq * 4 + 2];
        float go = sg[b][jl * 4 + 3] + p0v[jq * 4 + 3];
        float cn = sigm(gf) * c0r[jq] + sigm(gi) * tanhf(gg);
        float hn = sigm(go) * tanhf(cn);
        c0r[jq] = cn; h0k[jq] = hn;
        sh[b][jl] = (unsigned)f2bf(hn) | tA;
      }
    }
    __syncthreads();
    if (w == 0) {  // fire-and-forget: tags carry the ordering
      u64x2 v0 = *(const u64x2*)&sh[pb][pjh * 8];
      u64x2 v1 = *(const u64x2*)&sh[pb][pjh * 8 + 4];
      unsigned long long* dst =
          (unsigned long long*)(XH0 + pb * 512 + wg * 16 + pjh * 8);
      __hip_atomic_store(dst + 0, v0.x, RLX, AGT);
      __hip_atomic_store(dst + 1, v0.y, RLX, AGT);
      __hip_atomic_store(dst + 2, v1.x, RLX, AGT);
      __hip_atomic_store(dst + 3, v1.y, RLX, AGT);
    }

    // ================= phase B: layer 1 =================
    f32x4 aB0e = (f32x4){0.f,0.f,0.f,0.f}, aB0o = (f32x4){0.f,0.f,0.f,0.f};
    f32x4 aB1e = (f32x4){0.f,0.f,0.f,0.f}, aB1o = (f32x4){0.f,0.f,0.f,0.f};
    if (t == 0) {                          // half1 holds FOUT; need h1(-1)
      STAGE_INIT(H1I, 1);
      __syncthreads();
    }
    MFMA_HALF(Wr1p, 16, aB0e, aB0o, aB1e, aB1o);  // resident h1(t-1), half1

    STAGE_TAG(XH0, 0, (unsigned)(2 * t + 1));     // fresh h0(t) -> half0
    MFMA_HALF(Wr1p, 0, aB0e, aB0o, aB1e, aB1o);
    {
      f32x4 s0 = aB0e + aB0o, s1 = aB1e + aB1o;
#pragma unroll
      for (int r = 0; r < 4; ++r) {
        sg[fc * 4 + r][w * 16 + fr] = s0[r];
        sg[16 + fc * 4 + r][w * 16 + fr] = s1[r];
      }
    }
    __syncthreads();
    {
      const unsigned tB = (unsigned)(2 * t + 2) << 16;
#pragma unroll
      for (int jq = 0; jq < 2; ++jq) {
        const int jl = jl0 + jq * 8;
        float gi = sg[b][jl * 4 + 0] + b1v[jq * 4 + 0];
        float gf = sg[b][jl * 4 + 1] + b1v[jq * 4 + 1];
        float gg = sg[b][jl * 4 + 2] + b1v[jq * 4 + 2];
        float go = sg[b][jl * 4 + 3] + b1v[jq * 4 + 3];
        float cn = sigm(gf) * c1r[jq] + sigm(gi) * tanhf(gg);
        float hn = sigm(go) * tanhf(cn);
        c1r[jq] = cn; h1k[jq] = hn;
        sh[b][jl] = (unsigned)f2bf(hn) | tB;
      }
    }
    __syncthreads();
    if (w == 0) {
      u64x2 v0 = *(const u64x2*)&sh[pb][pjh * 8];
      u64x2 v1 = *(const u64x2*)&sh[pb][pjh * 8 + 4];
      unsigned long long* dst =
          (unsigned long long*)(XH1 + pb * 512 + wg * 16 + pjh * 8);
      __hip_atomic_store(dst + 0, v0.x, RLX, AGT);
      __hip_atomic_store(dst + 1, v0.y, RLX, AGT);
      __hip_atomic_store(dst + 2, v1.x, RLX, AGT);
      __hip_atomic_store(dst + 3, v1.y, RLX, AGT);
    } else if (w == 1) {  // out(t) to outbf (strip tags)
      const unsigned long long* s = (const unsigned long long*)&sh[pb][pjh * 8];
      unsigned long long q0 = s[0], q1 = s[1], q2 = s[2], q3 = s[3];
      u64x2 v;
      v.x = (unsigned long long)pack2(q0) | ((unsigned long long)pack2(q1) << 32);
      v.y = (unsigned long long)pack2(q2) | ((unsigned long long)pack2(q3) << 32);
      *(u64x2*)(outbf + (t * 32 + pb) * 512 + wg * 16 + pjh * 8) = v;
    }
  }
#undef STAGE_INIT
#undef STAGE_TAG
#undef MFMA_HALF

  // final state outputs
  float* hT = outs + 131072000;
  float* cT = outs + 131072000 + 32768;
  float* oT = outs + 131072000 + 65536;
#pragma unroll
  for (int jq = 0; jq < 2; ++jq) {
    const int j = wg * 16 + jl0 + jq * 8;
    hT[b * 512 + j] = h0k[jq];
    hT[16384 + b * 512 + j] = h1k[jq];
    cT[b * 512 + j] = c0r[jq];
    cT[16384 + b * 512 + j] = c1r[jq];
    oT[b * 512 + j] = h1k[jq];
  }
}

// ---------------------------------------------------------------------------
// lse: reduce 250 per-tile (max,sumexp) partials per row, then subtract
// ---------------------------------------------------------------------------
__global__ __launch_bounds__(256, 1) void lse_fix(float* __restrict__ sc,
                                                  const float2* __restrict__ pms)
{
  const long row = blockIdx.x;
  float4* p4 = (float4*)(sc + row * 32000L);
  const int tid = threadIdx.x;
  float m = -3.0e38f, s = 0.0f;
  if (tid < 250) {
    float2 p = pms[row * 250 + tid];
    m = p.x; s = p.y;
  }
#pragma unroll
  for (int off = 32; off > 0; off >>= 1) {
    float mo = __shfl_down(m, off);
    float so = __shfl_down(s, off);
    float mn = fmaxf(m, mo);
    s = s * __expf(m - mn) + so * __expf(mo - mn);
    m = mn;
  }
  __shared__ float lm[4], ls[4], lse_sh;
  if ((tid & 63) == 0) { lm[tid >> 6] = m; ls[tid >> 6] = s; }
  __syncthreads();
  if (tid == 0) {
    float M = lm[0], S = ls[0];
#pragma unroll
    for (int i = 1; i < 4; ++i) {
      float mn = fmaxf(M, lm[i]);
      S = S * __expf(M - mn) + ls[i] * __expf(lm[i] - mn);
      M = mn;
    }
    lse_sh = M + __logf(S);
  }
  __syncthreads();
  const float lse = lse_sh;
  for (int i = tid; i < 8000; i += 256) {
    float4 v = p4[i];
    v.x -= lse; v.y -= lse; v.z -= lse; v.w -= lse;
    p4[i] = v;
  }
}

// ---------------------------------------------------------------------------
extern "C" void kernel_launch(void* const* d_in, const int* in_sizes, int n_in,
                              void* d_out, int out_size, void* d_ws, size_t ws_size,
                              hipStream_t stream) {
  const int*   ids  = (const int*)d_in[0];
  const float* cd   = (const float*)d_in[1];
  const float* wemb = (const float*)d_in[2];
  const float* semb = (const float*)d_in[3];
  const float* h0   = (const float*)d_in[4];
  const float* c0   = (const float*)d_in[5];
  const float* pout = (const float*)d_in[6];
  const float* Wih0 = (const float*)d_in[7];
  const float* Whh0 = (const float*)d_in[8];
  const float* bih0 = (const float*)d_in[9];
  const float* bhh0 = (const float*)d_in[10];
  const float* Wih1 = (const float*)d_in[11];
  const float* Whh1 = (const float*)d_in[12];
  const float* bih1 = (const float*)d_in[13];
  const float* bhh1 = (const float*)d_in[14];
  const float* Wg   = (const float*)d_in[15];
  const float* bg   = (const float*)d_in[16];
  float* out = (float*)d_out;

  char* ws = (char*)d_ws;
  unsigned short* WgBf   = (unsigned short*)(ws);
  unsigned short* W0e    = (unsigned short*)(ws + 32768000);
  unsigned short* Wr0p   = (unsigned short*)(ws + 34865152);
  unsigned short* Wr1p   = (unsigned short*)(ws + 39059456);
  float*          b1p    = (float*)(ws + 43253760);
  float*          bias0c = (float*)(ws + 43261952);
  float*          wcd    = (float*)(ws + 43270144);
  unsigned short* embbf  = (unsigned short*)(ws + 43278336);
  unsigned short* outbf  = (unsigned short*)(ws + 47472640);
  float*          P0t    = (float*)(ws + 51666944);
  float*          PMS    = (float*)(ws + 51666944);   // aliases P0t (dead then)
  unsigned int*   XH0    = (unsigned int*)(ws + 85221376);
  unsigned int*   XH1    = (unsigned int*)(ws + 85286912);
  unsigned short* H0I    = (unsigned short*)(ws + 85352448);
  unsigned short* H1I    = (unsigned short*)(ws + 85385216);
  unsigned short* FOUT   = (unsigned short*)(ws + 85417984);

  // clear exchange tags every launch (no cross-call state)
  hipMemsetAsync((void*)XH0, 0, 131072, stream);

  prep_k<<<8192, 256, 0, stream>>>(Wg, Wih0, Whh0, Wih1, Whh1,
                                   bih0, bhh0, bih1, bhh1, h0, pout,
                                   WgBf, W0e, Wr0p, Wr1p, b1p, bias0c, wcd,
                                   H0I, H1I, FOUT);

  emb_k<<<4096, 256, 0, stream>>>(ids, wemb, semb, embbf);

  // P0t[perm(g)][tb] = W0e @ emb^T + bias0 + cd*wcd   (M=2048, N=4096)
  gemm_bt<0><<<512, 256, 0, stream>>>(W0e, embbf, 4096, P0t, bias0c, wcd, cd);

  lstm_seq<<<32, 256, 0, stream>>>(Wr0p, Wr1p, P0t, b1p, c0,
                                   XH0, XH1, H0I, H1I, FOUT, outbf, out);

  // logits[tb][v] = out_all @ Wg^T + bg; partial (max,sumexp) -> PMS
  gemm_bt<1><<<8000, 256, 0, stream>>>(outbf, WgBf, 32000, out, bg, PMS, nullptr);

  lse_fix<<<4096, 256, 0, stream>>>(out, (const float2*)PMS);
}

// Round 8
// 2418.773 us; speedup vs baseline: 1.1521x; 1.1521x over previous
//
#include <hip/hip_runtime.h>
#include <hip/hip_bf16.h>

// RNNDecoder: emb -> 2-layer LSTM (seq over T=128) -> generator + log_softmax
// T=128 B=32 E=512 H=512 G=2048 V=32000
//
// R8: lean tag-embedded exchange on the R5 skeleton.
//  - XH0/XH1 u32[32wg][32b][16j] = {bf16 h | u16 tag}, exclusive 2KB/WG blocks.
//    Producers fire relaxed stores, NO drain/flags. Consumers stage-with-retry
//    in 4 independent batches of 8 u64/thread (16 VGPR), retrying only
//    unfinished batches, no barrier in the retry loop.
//  - Tags: XH0 gets 2t+1 (A(t) output), XH1 gets 2t+2 (B(t) output); XH1 init
//    {prev_output|0} written by prep covers A(0). XH0/XH1 memset 0xFF per
//    launch (stale tag 255/256 from a previous replay can never match).
//  - Keep R7 gemm<1> (max,sumexp)-partial epilogue + partial-reduce lse_fix.
//
// ws layout (bytes):
//  [0)         WgBf  bf16[32000][512]   32,768,000
//  [32768000)  W0e   bf16[2048][512]     2,097,152
//  [34865152)  Wr0p  bf16[2048][1024]    4,194,304
//  [39059456)  Wr1p  bf16[2048][1024]    4,194,304
//  [43253760)  b1p   f32[2048]               8,192
//  [43261952)  bias0c f32[2048]              8,192
//  [43270144)  wcd   f32[2048]               8,192
//  [43278336)  embbf bf16[4096][512]     4,194,304
//  [47472640)  outbf bf16[4096][512]     4,194,304
//  [51666944)  P0t   f32[2048][4096]    33,554,432  (aliased by PMS f32x2[4096][250])
//  [85221376)  XH0   u32[32][32][16]        65,536
//  [85286912)  XH1   u32[32][32][16]        65,536
//  [85352448)  H0I   bf16[32][512]          32,768
//  [85385216)  H1I   bf16[32][512]          32,768
// total 85,417,984

typedef __attribute__((ext_vector_type(8))) short bf16x8;
typedef __attribute__((ext_vector_type(4))) float f32x4;
typedef __attribute__((ext_vector_type(2))) unsigned long long u64x2;

#define AS1 __attribute__((address_space(1)))
#define AS3 __attribute__((address_space(3)))
#define RLX __ATOMIC_RELAXED
#define AGT __HIP_MEMORY_SCOPE_AGENT

__device__ __forceinline__ unsigned short f2bf(float f) {
  unsigned int u = __builtin_bit_cast(unsigned int, f);
  u += 0x7fffu + ((u >> 16) & 1u);            // round-to-nearest-even
  return (unsigned short)(u >> 16);
}

__device__ __forceinline__ void gl16(const void* g, void* l) {
  __builtin_amdgcn_global_load_lds((const AS1 unsigned int*)g,
                                   (AS3 unsigned int*)l, 16, 0, 0);
}

__device__ __forceinline__ float sigm(float x) { return 1.0f / (1.0f + __expf(-x)); }

// both u32s of a u64 carry tag 'want' in their high 16 bits?
__device__ __forceinline__ bool chk2(unsigned long long q, unsigned want) {
  return (((unsigned)(q >> 16) & 0xffffu) == want) &&
         (((unsigned)(q >> 48) & 0xffffu) == want);
}
// pack the two low-16 payloads of a u64 into one u32
__device__ __forceinline__ unsigned pack2(unsigned long long q) {
  return ((unsigned)q & 0xffffu) | (((unsigned)(q >> 32) & 0xffffu) << 16);
}

// ---------------------------------------------------------------------------
// prep: dtype conversion + weight re-layout + initial state buffers
// ---------------------------------------------------------------------------
__global__ __launch_bounds__(256, 1) void prep_k(
    const float* __restrict__ Wg,  const float* __restrict__ Wih0,
    const float* __restrict__ Whh0,const float* __restrict__ Wih1,
    const float* __restrict__ Whh1,const float* __restrict__ bih0,
    const float* __restrict__ bhh0,const float* __restrict__ bih1,
    const float* __restrict__ bhh1,const float* __restrict__ h0,
    const float* __restrict__ pout,
    unsigned short* __restrict__ WgBf, unsigned short* __restrict__ W0e,
    unsigned short* __restrict__ Wr0p, unsigned short* __restrict__ Wr1p,
    float* __restrict__ b1p, float* __restrict__ bias0c,
    float* __restrict__ wcd, unsigned short* __restrict__ H0I,
    unsigned short* __restrict__ H1I, unsigned int* __restrict__ XH1)
{
  const long N0 = 16384000L;           // WgBf
  const long N1 = N0 + 1048576L;       // W0e
  const long N2 = N1 + 2097152L;       // Wr0p
  const long N3 = N2 + 2097152L;       // Wr1p
  const long N4 = N3 + 2048L;          // b1p
  const long N5 = N4 + 2048L;          // bias0c
  const long N6 = N5 + 2048L;          // wcd
  const long N7 = N6 + 49152L;         // state inits (3 x 16384)
  for (long i = blockIdx.x * 256L + threadIdx.x; i < N7; i += 256L * gridDim.x) {
    if (i < N0) {
      WgBf[i] = f2bf(Wg[i]);
    } else if (i < N1) {
      long k = i - N0; int g = (int)(k >> 9); int kk = (int)(k & 511);
      W0e[k] = f2bf(Wih0[g * 1025 + kk]);
    } else if (i < N2) {
      long k = i - N1; int gp = (int)(k >> 10); int kk = (int)(k & 1023);
      int j = gp >> 2, gate = gp & 3; int g = gate * 512 + j;
      float v = (kk < 512) ? Whh0[g * 512 + kk] : Wih0[g * 1025 + 513 + (kk - 512)];
      Wr0p[k] = f2bf(v);
    } else if (i < N3) {
      long k = i - N2; int gp = (int)(k >> 10); int kk = (int)(k & 1023);
      int j = gp >> 2, gate = gp & 3; int g = gate * 512 + j;
      float v = (kk < 512) ? Wih1[g * 512 + kk] : Whh1[g * 512 + (kk - 512)];
      Wr1p[k] = f2bf(v);
    } else if (i < N4) {
      int gp = (int)(i - N3); int j = gp >> 2, gate = gp & 3; int g = gate * 512 + j;
      b1p[gp] = bih1[g] + bhh1[g];
    } else if (i < N5) {
      int g = (int)(i - N4); bias0c[g] = bih0[g] + bhh0[g];
    } else if (i < N6) {
      int g = (int)(i - N5); wcd[g] = Wih0[g * 1025 + 512];
    } else {
      long k = i - N6;                 // 0..49151
      int sub = (int)(k >> 14);        // 0=H0I, 1=H1I, 2=XH1 tagged init
      int e = (int)(k & 16383);
      if (sub < 2) {
        int b = e >> 9, j = e & 511;
        float v = (sub == 0) ? h0[b * 512 + j] : h0[16384 + b * 512 + j];
        ((sub == 0) ? H0I : H1I)[e] = f2bf(v);
      } else {
        // XH1[wg][b][jl] = {bf16(prev_output[b][wg*16+jl]) | tag 0}
        int wgx = e >> 9, b = (e >> 4) & 31, jl = e & 15;
        XH1[e] = (unsigned)f2bf(pout[b * 512 + wgx * 16 + jl]);
      }
    }
  }
}

// ---------------------------------------------------------------------------
// embedding
// ---------------------------------------------------------------------------
__global__ __launch_bounds__(256, 1) void emb_k(
    const int* __restrict__ ids, const float* __restrict__ wemb,
    const float* __restrict__ semb, unsigned short* __restrict__ ebf)
{
  const int tb = blockIdx.x;
  const int id = ids[tb];
  const int sp = (id < 3) ? (id + 1) : 0;
  const float* wr = wemb + (long)id * 512;
  const float* sr = semb + sp * 512;
  for (int i = threadIdx.x; i < 512; i += 256)
    ebf[tb * 512 + i] = f2bf(wr[i] + sr[i]);
}

// ---------------------------------------------------------------------------
// GEMM: D[m][n] = sum_k A[m][k]*B[n][k]  (A [M][512] bf16, B [N][512] bf16)
// EPI==0: P0t path (permuted rows + bias + countdown term)
// EPI==1: generator: C = logits+bg, plus per-(row, n-tile) (max,sumexp)
//         partials into PMS (passed via e1)
// ---------------------------------------------------------------------------
template<int EPI>
__global__ __launch_bounds__(256, 1) void gemm_bt(
    const unsigned short* __restrict__ A,
    const unsigned short* __restrict__ B, int N,
    float* __restrict__ C,
    const float* __restrict__ e0, float* __restrict__ e1,
    const float* __restrict__ e2)
{
  __shared__ unsigned short sA[4096];
  __shared__ unsigned short sB[4096];
  __shared__ float pmw[128][2][2];
  const int tid = threadIdx.x;
  const int l = tid & 63, w = tid >> 6;
  const int nb = N >> 7;
  const int bid = blockIdx.x;
  const int bm = bid / nb, bn = bid - bm * nb;

  const int u0 = w * 128 + l;
  const int u1 = u0 + 64;
  const int r0 = u0 >> 2, c0 = (u0 & 3) ^ (r0 & 3);
  const int r1 = u1 >> 2, c1 = (u1 & 3) ^ (r1 & 3);
  const unsigned short* ga0 = A + (long)(bm * 128 + r0) * 512 + c0 * 8;
  const unsigned short* ga1 = A + (long)(bm * 128 + r1) * 512 + c1 * 8;
  const unsigned short* gb0 = B + (long)(bn * 128 + r0) * 512 + c0 * 8;
  const unsigned short* gb1 = B + (long)(bn * 128 + r1) * 512 + c1 * 8;
  unsigned short* la0 = sA + (w * 2 + 0) * 512;
  unsigned short* la1 = sA + (w * 2 + 1) * 512;
  unsigned short* lb0 = sB + (w * 2 + 0) * 512;
  unsigned short* lb1 = sB + (w * 2 + 1) * 512;

  const int fr = l & 15, fc = l >> 4;
  const int wm = w >> 1, wn = w & 1;
  int aoff[4], boff[4];
#pragma unroll
  for (int mi = 0; mi < 4; ++mi) {
    int row = wm * 64 + mi * 16 + fr;
    aoff[mi] = row * 64 + ((fc ^ (row & 3)) * 16);
  }
#pragma unroll
  for (int ni = 0; ni < 4; ++ni) {
    int row = wn * 64 + ni * 16 + fr;
    boff[ni] = row * 64 + ((fc ^ (row & 3)) * 16);
  }

  f32x4 acc[4][4];
#pragma unroll
  for (int i = 0; i < 4; ++i)
#pragma unroll
    for (int jq = 0; jq < 4; ++jq) acc[i][jq] = (f32x4){0.f, 0.f, 0.f, 0.f};

  for (int kt = 0; kt < 16; ++kt) {
    __syncthreads();
    gl16(ga0 + kt * 32, la0);
    gl16(ga1 + kt * 32, la1);
    gl16(gb0 + kt * 32, lb0);
    gl16(gb1 + kt * 32, lb1);
    asm volatile("s_waitcnt vmcnt(0)" ::: "memory");
    __syncthreads();
    bf16x8 av[4], bv[4];
#pragma unroll
    for (int mi = 0; mi < 4; ++mi)
      av[mi] = *(const bf16x8*)((const char*)sA + aoff[mi]);
#pragma unroll
    for (int ni = 0; ni < 4; ++ni)
      bv[ni] = *(const bf16x8*)((const char*)sB + boff[ni]);
#pragma unroll
    for (int mi = 0; mi < 4; ++mi)
#pragma unroll
      for (int ni = 0; ni < 4; ++ni)
        acc[mi][ni] = __builtin_amdgcn_mfma_f32_16x16x32_bf16(av[mi], bv[ni], acc[mi][ni], 0, 0, 0);
  }

  const int mbase = bm * 128 + wm * 64;
  const int nbase = bn * 128 + wn * 64;

  if (EPI == 0) {
#pragma unroll
    for (int mi = 0; mi < 4; ++mi)
#pragma unroll
      for (int ni = 0; ni < 4; ++ni) {
        const int col = nbase + ni * 16 + fr;
#pragma unroll
        for (int r = 0; r < 4; ++r) {
          const int row = mbase + mi * 16 + fc * 4 + r;
          const int gp = ((row & 511) << 2) | (row >> 9);
          float v = acc[mi][ni][r] + e0[row] + e2[col] * e1[row];
          C[(long)gp * N + col] = v;
        }
      }
  } else {
    float m2[4][4], s2[4][4];
#pragma unroll
    for (int mi = 0; mi < 4; ++mi)
#pragma unroll
      for (int r = 0; r < 4; ++r) { m2[mi][r] = -3.0e38f; s2[mi][r] = 0.f; }
#pragma unroll
    for (int mi = 0; mi < 4; ++mi)
#pragma unroll
      for (int ni = 0; ni < 4; ++ni) {
        const int col = nbase + ni * 16 + fr;
        const float bgc = e0[col];
#pragma unroll
        for (int r = 0; r < 4; ++r) {
          float v = acc[mi][ni][r] + bgc;
          acc[mi][ni][r] = v;
          C[(long)(mbase + mi * 16 + fc * 4 + r) * N + col] = v;
          m2[mi][r] = fmaxf(m2[mi][r], v);
        }
      }
#pragma unroll
    for (int mi = 0; mi < 4; ++mi)
#pragma unroll
      for (int r = 0; r < 4; ++r)
#pragma unroll
        for (int s = 1; s < 16; s <<= 1)
          m2[mi][r] = fmaxf(m2[mi][r], __shfl_xor(m2[mi][r], s));
#pragma unroll
    for (int mi = 0; mi < 4; ++mi)
#pragma unroll
      for (int ni = 0; ni < 4; ++ni)
#pragma unroll
        for (int r = 0; r < 4; ++r)
          s2[mi][r] += __expf(acc[mi][ni][r] - m2[mi][r]);
#pragma unroll
    for (int mi = 0; mi < 4; ++mi)
#pragma unroll
      for (int r = 0; r < 4; ++r)
#pragma unroll
        for (int s = 1; s < 16; s <<= 1)
          s2[mi][r] += __shfl_xor(s2[mi][r], s);
    if (fr == 0) {
#pragma unroll
      for (int mi = 0; mi < 4; ++mi)
#pragma unroll
        for (int r = 0; r < 4; ++r) {
          const int rl = wm * 64 + mi * 16 + fc * 4 + r;
          pmw[rl][wn][0] = m2[mi][r];
          pmw[rl][wn][1] = s2[mi][r];
        }
    }
    __syncthreads();
    if (tid < 128) {
      float ma = pmw[tid][0][0], sa = pmw[tid][0][1];
      float mb = pmw[tid][1][0], sb = pmw[tid][1][1];
      float M = fmaxf(ma, mb);
      float S = sa * __expf(ma - M) + sb * __expf(mb - M);
      float2* PMS = (float2*)e1;
      float2 o; o.x = M; o.y = S;
      PMS[(long)(bm * 128 + tid) * nb + bn] = o;
    }
  }
}

// ---------------------------------------------------------------------------
// Persistent sequential LSTM. 32 WGs x 256 thr (4 waves). WG owns gate rows
// [wg*64, wg*64+64) i.e. j in [wg*16, wg*16+16).
// Exchange: XH0/XH1 u32[32wg][32b][16jl] = {bf16 | u16 tag}, 2KB exclusive
// block per WG. A(t) -> XH0 tag 2t+1; B(t) -> XH1 tag 2t+2; XH1 init tag 0.
// Consumers stage-with-retry, 4 batches x 8 u64/thread, no drains, no flags.
// sx LDS [32 b][1024 cols] persists: half0 = h0, half1 = h1/out.
// ---------------------------------------------------------------------------
__global__ __launch_bounds__(256, 1) void lstm_seq(
    const unsigned short* __restrict__ Wr0p,
    const unsigned short* __restrict__ Wr1p,
    const float* __restrict__ P0t, const float* __restrict__ b1p,
    const float* __restrict__ c0in,
    unsigned int* __restrict__ XH0, unsigned int* __restrict__ XH1,
    const unsigned short* __restrict__ H0I, const unsigned short* __restrict__ H1I,
    unsigned short* __restrict__ outbf, float* __restrict__ outs)
{
  const int tid = threadIdx.x;
  const int wg = blockIdx.x;            // 32
  const int l = tid & 63, w = tid >> 6;
  const int fr = l & 15, fc = l >> 4;

  __shared__ unsigned short sx[32768];  // 64KB: [32 b][1024 cols], swizzled
  __shared__ float sg[32][65];
  __shared__ unsigned sh[32][16];       // packed {value|tag}

  const int b = tid & 31, jl0 = tid >> 5;       // thread owns jl0, jl0+8

  float c0r[2], c1r[2], h0k[2], h1k[2];
#pragma unroll
  for (int jq = 0; jq < 2; ++jq) {
    c0r[jq] = c0in[b * 512 + wg * 16 + jl0 + jq * 8];
    c1r[jq] = c0in[16384 + b * 512 + wg * 16 + jl0 + jq * 8];
    h0k[jq] = 0.f; h1k[jq] = 0.f;
  }

  float b1v[8];
#pragma unroll
  for (int jq = 0; jq < 2; ++jq)
#pragma unroll
    for (int g = 0; g < 4; ++g)
      b1v[jq * 4 + g] = b1p[(wg * 16 + jl0 + jq * 8) * 4 + g];

  // MFMA addressing
  const char* sxb0 = (const char*)sx + fr * 2048;          // b-rows 0-15
  const char* sxb1 = (const char*)sx + (16 + fr) * 2048;   // b-rows 16-31
  const int xr = (fr & 7) << 4;
  const int wrow = (wg * 64 + w * 16 + fr) * 1024 + fc * 8;

  // producer store lane mapping (w0/w1): lane -> (batch row, j-half)
  const int pb = l >> 1, pjh = l & 1;

// ---- tagless init stage: src bf16[32][512] (b-major) -> sx half ----
#define STAGE_INIT(srcp, half)                                                \
  do {                                                                        \
    _Pragma("unroll")                                                         \
    for (int i = 0; i < 8; ++i) {                                             \
      int u = i * 256 + tid;                                                  \
      u64x2 v = *(const u64x2*)((srcp) + u * 8);                              \
      int bb = u >> 6, j2 = (u & 63) * 16;                                    \
      *(u64x2*)((char*)sx + bb * 2048 + ((((half) * 1024) + j2) ^ ((bb & 7) << 4))) = v; \
    }                                                                         \
  } while (0)

// ---- tagged stage with per-batch retry: src u32[32][32][16] -> sx half ----
// thread's u64 #(ba*8+i) = source wg (ba*8+i), b=tid>>3, jl=(tid&7)*2 (+1)
#define STAGE_TAG(srcp, half, want)                                           \
  do {                                                                        \
    unsigned pend = 0xFu;                                                     \
    const int bofs = (half) * 1024 + ((tid & 7) * 4);                         \
    char* const lbase = (char*)sx + (tid >> 3) * 2048;                        \
    const int lswz = ((tid >> 3) & 7) << 4;                                   \
    while (pend) {                                                            \
      _Pragma("unroll")                                                       \
      for (int ba = 0; ba < 4; ++ba) {                                        \
        if (!(pend & (1u << ba))) continue;                                   \
        unsigned long long q[8];                                              \
        _Pragma("unroll")                                                     \
        for (int i = 0; i < 8; ++i)                                           \
          q[i] = __hip_atomic_load((const unsigned long long*)(srcp)          \
                     + (ba * 2048 + i * 256 + tid), RLX, AGT);                \
        bool ok = true;                                                       \
        _Pragma("unroll")                                                     \
        for (int i = 0; i < 8; ++i) ok = ok && chk2(q[i], (unsigned)(want));  \
        if (ok) {                                                             \
          _Pragma("unroll")                                                   \
          for (int i = 0; i < 8; ++i) {                                       \
            int cb = bofs + (ba * 8 + i) * 32;                                \
            *(unsigned*)(lbase + (cb ^ lswz)) = pack2(q[i]);                  \
          }                                                                   \
          pend &= ~(1u << ba);                                                \
        }                                                                     \
      }                                                                       \
      if (pend) __builtin_amdgcn_s_sleep(1);                                  \
    }                                                                         \
    __syncthreads();                                                          \
  } while (0)

// split even/odd kt accumulators: dependent chain 16 -> 8
#define MFMA_HALF(Wp, k0, e0v, o0v, e1v, o1v)                                 \
  do {                                                                        \
    _Pragma("unroll")                                                         \
    for (int kp = 0; kp < 8; ++kp) {                                          \
      int kta = (k0) + kp * 2, ktb = kta + 1;                                 \
      bf16x8 bva = *(const bf16x8*)((Wp) + wrow + kta * 32);                  \
      bf16x8 x0a = *(const bf16x8*)(sxb0 + ((kta * 64 + fc * 16) ^ xr));      \
      bf16x8 x1a = *(const bf16x8*)(sxb1 + ((kta * 64 + fc * 16) ^ xr));      \
      e0v = __builtin_amdgcn_mfma_f32_16x16x32_bf16(x0a, bva, e0v, 0, 0, 0);  \
      e1v = __builtin_amdgcn_mfma_f32_16x16x32_bf16(x1a, bva, e1v, 0, 0, 0);  \
      bf16x8 bvb = *(const bf16x8*)((Wp) + wrow + ktb * 32);                  \
      bf16x8 x0b = *(const bf16x8*)(sxb0 + ((ktb * 64 + fc * 16) ^ xr));      \
      bf16x8 x1b = *(const bf16x8*)(sxb1 + ((ktb * 64 + fc * 16) ^ xr));      \
      o0v = __builtin_amdgcn_mfma_f32_16x16x32_bf16(x0b, bvb, o0v, 0, 0, 0);  \
      o1v = __builtin_amdgcn_mfma_f32_16x16x32_bf16(x1b, bvb, o1v, 0, 0, 0);  \
    }                                                                         \
  } while (0)

  // ---- pre-loop: stage h0 init into half0 ----
  STAGE_INIT(H0I, 0);
  __syncthreads();

  for (int t = 0; t < 128; ++t) {
    // ================= phase A: layer 0 =================
    float p0v[8];
#pragma unroll
    for (int jq = 0; jq < 2; ++jq)
#pragma unroll
      for (int g = 0; g < 4; ++g)
        p0v[jq * 4 + g] =
            P0t[(long)((wg * 16 + jl0 + jq * 8) * 4 + g) * 4096 + t * 32 + b];

    f32x4 aA0e = (f32x4){0.f,0.f,0.f,0.f}, aA0o = (f32x4){0.f,0.f,0.f,0.f};
    f32x4 aA1e = (f32x4){0.f,0.f,0.f,0.f}, aA1o = (f32x4){0.f,0.f,0.f,0.f};
    MFMA_HALF(Wr0p, 0, aA0e, aA0o, aA1e, aA1o);   // resident h0(t-1), half0

    STAGE_TAG(XH1, 1, 2 * t);                     // h1(t-1)/out(t-1) (init t=0)
    MFMA_HALF(Wr0p, 16, aA0e, aA0o, aA1e, aA1o);  // fresh half1
    {
      f32x4 s0 = aA0e + aA0o, s1 = aA1e + aA1o;
#pragma unroll
      for (int r = 0; r < 4; ++r) {
        sg[fc * 4 + r][w * 16 + fr] = s0[r];
        sg[16 + fc * 4 + r][w * 16 + fr] = s1[r];
      }
    }
    __syncthreads();
    {
      const unsigned tA = (unsigned)(2 * t + 1) << 16;
#pragma unroll
      for (int jq = 0; jq < 2; ++jq) {
        const int jl = jl0 + jq * 8;
        float gi = sg[b][jl * 4 + 0] + p0v[jq * 4 + 0];
        float gf = sg[b][jl * 4 + 1] + p0v[jq * 4 + 1];
        float gg = sg[b][jl * 4 + 2] + p0v[jq * 4 + 2];
        float go = sg[b][jl * 4 + 3] + p0v[jq * 4 + 3];
        float cn = sigm(gf) * c0r[jq] + sigm(gi) * tanhf(gg);
        float hn = sigm(go) * tanhf(cn);
        c0r[jq] = cn; h0k[jq] = hn;
        sh[b][jl] = (unsigned)f2bf(hn) | tA;
      }
    }
    __syncthreads();
    if (w == 0) {  // fire-and-forget tagged stores, exclusive 2KB block
      const unsigned long long* s = (const unsigned long long*)&sh[pb][pjh * 8];
      unsigned long long* dst = (unsigned long long*)(XH0 + wg * 512) + l * 4;
      __hip_atomic_store(dst + 0, s[0], RLX, AGT);
      __hip_atomic_store(dst + 1, s[1], RLX, AGT);
      __hip_atomic_store(dst + 2, s[2], RLX, AGT);
      __hip_atomic_store(dst + 3, s[3], RLX, AGT);
    }

    // ================= phase B: layer 1 =================
    f32x4 aB0e = (f32x4){0.f,0.f,0.f,0.f}, aB0o = (f32x4){0.f,0.f,0.f,0.f};
    f32x4 aB1e = (f32x4){0.f,0.f,0.f,0.f}, aB1o = (f32x4){0.f,0.f,0.f,0.f};
    if (t == 0) {                          // half1 holds out(-1); need h1(-1)
      STAGE_INIT(H1I, 1);
      __syncthreads();
    }
    MFMA_HALF(Wr1p, 16, aB0e, aB0o, aB1e, aB1o);  // resident h1(t-1), half1

    STAGE_TAG(XH0, 0, 2 * t + 1);                 // fresh h0(t) -> half0
    MFMA_HALF(Wr1p, 0, aB0e, aB0o, aB1e, aB1o);
    {
      f32x4 s0 = aB0e + aB0o, s1 = aB1e + aB1o;
#pragma unroll
      for (int r = 0; r < 4; ++r) {
        sg[fc * 4 + r][w * 16 + fr] = s0[r];
        sg[16 + fc * 4 + r][w * 16 + fr] = s1[r];
      }
    }
    __syncthreads();
    {
      const unsigned tB = (unsigned)(2 * t + 2) << 16;
#pragma unroll
      for (int jq = 0; jq < 2; ++jq) {
        const int jl = jl0 + jq * 8;
        float gi = sg[b][jl * 4 + 0] + b1v[jq * 4 + 0];
        float gf = sg[b][jl * 4 + 1] + b1v[jq * 4 + 1];
        float gg = sg[b][jl * 4 + 2] + b1v[jq * 4 + 2];
        float go = sg[b][jl * 4 + 3] + b1v[jq * 4 + 3];
        float cn = sigm(gf) * c1r[jq] + sigm(gi) * tanhf(gg);
        float hn = sigm(go) * tanhf(cn);
        c1r[jq] = cn; h1k[jq] = hn;
        sh[b][jl] = (unsigned)f2bf(hn) | tB;
      }
    }
    __syncthreads();
    if (w == 0) {
      const unsigned long long* s = (const unsigned long long*)&sh[pb][pjh * 8];
      unsigned long long* dst = (unsigned long long*)(XH1 + wg * 512) + l * 4;
      __hip_atomic_store(dst + 0, s[0], RLX, AGT);
      __hip_atomic_store(dst + 1, s[1], RLX, AGT);
      __hip_atomic_store(dst + 2, s[2], RLX, AGT);
      __hip_atomic_store(dst + 3, s[3], RLX, AGT);
    } else if (w == 1) {  // out(t) to outbf (strip tags)
      const unsigned long long* s = (const unsigned long long*)&sh[pb][pjh * 8];
      unsigned long long q0 = s[0], q1 = s[1], q2 = s[2], q3 = s[3];
      u64x2 v;
      v.x = (unsigned long long)pack2(q0) | ((unsigned long long)pack2(q1) << 32);
      v.y = (unsigned long long)pack2(q2) | ((unsigned long long)pack2(q3) << 32);
      *(u64x2*)(outbf + (t * 32 + pb) * 512 + wg * 16 + pjh * 8) = v;
    }
  }
#undef STAGE_INIT
#undef STAGE_TAG
#undef MFMA_HALF

  // final state outputs
  float* hT = outs + 131072000;
  float* cT = outs + 131072000 + 32768;
  float* oT = outs + 131072000 + 65536;
#pragma unroll
  for (int jq = 0; jq < 2; ++jq) {
    const int j = wg * 16 + jl0 + jq * 8;
    hT[b * 512 + j] = h0k[jq];
    hT[16384 + b * 512 + j] = h1k[jq];
    cT[b * 512 + j] = c0r[jq];
    cT[16384 + b * 512 + j] = c1r[jq];
    oT[b * 512 + j] = h1k[jq];
  }
}

// ---------------------------------------------------------------------------
// lse: reduce 250 per-tile (max,sumexp) partials per row, then subtract
// ---------------------------------------------------------------------------
__global__ __launch_bounds__(256, 1) void lse_fix(float* __restrict__ sc,
                                                  const float2* __restrict__ pms)
{
  const long row = blockIdx.x;
  float4* p4 = (float4*)(sc + row * 32000L);
  const int tid = threadIdx.x;
  float m = -3.0e38f, s = 0.0f;
  if (tid < 250) {
    float2 p = pms[row * 250 + tid];
    m = p.x; s = p.y;
  }
#pragma unroll
  for (int off = 32; off > 0; off >>= 1) {
    float mo = __shfl_down(m, off);
    float so = __shfl_down(s, off);
    float mn = fmaxf(m, mo);
    s = s * __expf(m - mn) + so * __expf(mo - mn);
    m = mn;
  }
  __shared__ float lm[4], ls[4], lse_sh;
  if ((tid & 63) == 0) { lm[tid >> 6] = m; ls[tid >> 6] = s; }
  __syncthreads();
  if (tid == 0) {
    float M = lm[0], S = ls[0];
#pragma unroll
    for (int i = 1; i < 4; ++i) {
      float mn = fmaxf(M, lm[i]);
      S = S * __expf(M - mn) + ls[i] * __expf(lm[i] - mn);
      M = mn;
    }
    lse_sh = M + __logf(S);
  }
  __syncthreads();
  const float lse = lse_sh;
  for (int i = tid; i < 8000; i += 256) {
    float4 v = p4[i];
    v.x -= lse; v.y -= lse; v.z -= lse; v.w -= lse;
    p4[i] = v;
  }
}

// ---------------------------------------------------------------------------
extern "C" void kernel_launch(void* const* d_in, const int* in_sizes, int n_in,
                              void* d_out, int out_size, void* d_ws, size_t ws_size,
                              hipStream_t stream) {
  const int*   ids  = (const int*)d_in[0];
  const float* cd   = (const float*)d_in[1];
  const float* wemb = (const float*)d_in[2];
  const float* semb = (const float*)d_in[3];
  const float* h0   = (const float*)d_in[4];
  const float* c0   = (const float*)d_in[5];
  const float* pout = (const float*)d_in[6];
  const float* Wih0 = (const float*)d_in[7];
  const float* Whh0 = (const float*)d_in[8];
  const float* bih0 = (const float*)d_in[9];
  const float* bhh0 = (const float*)d_in[10];
  const float* Wih1 = (const float*)d_in[11];
  const float* Whh1 = (const float*)d_in[12];
  const float* bih1 = (const float*)d_in[13];
  const float* bhh1 = (const float*)d_in[14];
  const float* Wg   = (const float*)d_in[15];
  const float* bg   = (const float*)d_in[16];
  float* out = (float*)d_out;

  char* ws = (char*)d_ws;
  unsigned short* WgBf   = (unsigned short*)(ws);
  unsigned short* W0e    = (unsigned short*)(ws + 32768000);
  unsigned short* Wr0p   = (unsigned short*)(ws + 34865152);
  unsigned short* Wr1p   = (unsigned short*)(ws + 39059456);
  float*          b1p    = (float*)(ws + 43253760);
  float*          bias0c = (float*)(ws + 43261952);
  float*          wcd    = (float*)(ws + 43270144);
  unsigned short* embbf  = (unsigned short*)(ws + 43278336);
  unsigned short* outbf  = (unsigned short*)(ws + 47472640);
  float*          P0t    = (float*)(ws + 51666944);
  float*          PMS    = (float*)(ws + 51666944);   // aliases P0t (dead then)
  unsigned int*   XH0    = (unsigned int*)(ws + 85221376);
  unsigned int*   XH1    = (unsigned int*)(ws + 85286912);
  unsigned short* H0I    = (unsigned short*)(ws + 85352448);
  unsigned short* H1I    = (unsigned short*)(ws + 85385216);

  // poison exchange tags to 0xFFFF (never a valid want) every launch
  hipMemsetAsync((void*)XH0, 0xFF, 131072, stream);

  prep_k<<<8192, 256, 0, stream>>>(Wg, Wih0, Whh0, Wih1, Whh1,
                                   bih0, bhh0, bih1, bhh1, h0, pout,
                                   WgBf, W0e, Wr0p, Wr1p, b1p, bias0c, wcd,
                                   H0I, H1I, XH1);

  emb_k<<<4096, 256, 0, stream>>>(ids, wemb, semb, embbf);

  // P0t[perm(g)][tb] = W0e @ emb^T + bias0 + cd*wcd   (M=2048, N=4096)
  gemm_bt<0><<<512, 256, 0, stream>>>(W0e, embbf, 4096, P0t, bias0c, wcd, cd);

  lstm_seq<<<32, 256, 0, stream>>>(Wr0p, Wr1p, P0t, b1p, c0,
                                   XH0, XH1, H0I, H1I, outbf, out);

  // logits[tb][v] = out_all @ Wg^T + bg; partial (max,sumexp) -> PMS
  gemm_bt<1><<<8000, 256, 0, stream>>>(outbf, WgBf, 32000, out, bg, PMS, nullptr);

  lse_fix<<<4096, 256, 0, stream>>>(out, (const float2*)PMS);
}

// Round 10
// 1911.443 us; speedup vs baseline: 1.4578x; 1.2654x over previous
//
#include <hip/hip_runtime.h>
#include <hip/hip_bf16.h>

// RNNDecoder: emb -> 2-layer LSTM (seq over T=128) -> generator + log_softmax
// T=128 B=32 E=512 H=512 G=2048 V=32000
//
// R10: consolidation after R9's hang (XCD-local exchange unsafe in harness).
//  - lstm_seq: EXACT R5 structure (best measured: 1337us). Agent-scope relaxed
//    atomics, drain+flag, resident/fresh LDS halves, 32 WGs, single-buffer
//    exchange with transitive-safety.
//  - Tail: R8's gemm<1> per-(row,tile) (max,sumexp) partials -> PMS (aliases
//    dead P0t) + lse_fix partial-reduce (proven, ~45-50us).
//
// ws layout (bytes):
//  [0)         WgBf  bf16[32000][512]   32,768,000
//  [32768000)  W0e   bf16[2048][512]     2,097,152
//  [34865152)  Wr0p  bf16[2048][1024]    4,194,304
//  [39059456)  Wr1p  bf16[2048][1024]    4,194,304
//  [43253760)  b1p   f32[2048]               8,192
//  [43261952)  bias0c f32[2048]              8,192
//  [43270144)  wcd   f32[2048]               8,192
//  [43278336)  embbf bf16[4096][512]     4,194,304
//  [47472640)  outbf bf16[4096][512]     4,194,304
//  [51666944)  P0t   f32[2048][4096]    33,554,432  (aliased by PMS f32x2[4096][250])
//  [85221376)  flagA u32[32*32]              4,096
//  [85225472)  flagB u32[32*32]              4,096
//  [85229568)  H0X  bf16[32wg][32b][16j]    32,768
//  [85262336)  H1X  bf16[32wg][32b][16j]    32,768
//  [85295104)  FOUT bf16[32wg][32b][16j]    32,768
//  [85327872)  H1I  bf16[32wg][32b][16j]    32,768
// total 85,360,640

typedef __attribute__((ext_vector_type(8))) short bf16x8;
typedef __attribute__((ext_vector_type(4))) float f32x4;
typedef __attribute__((ext_vector_type(2))) unsigned long long u64x2;

#define AS1 __attribute__((address_space(1)))
#define AS3 __attribute__((address_space(3)))
#define RLX __ATOMIC_RELAXED
#define AGT __HIP_MEMORY_SCOPE_AGENT

__device__ __forceinline__ unsigned short f2bf(float f) {
  unsigned int u = __builtin_bit_cast(unsigned int, f);
  u += 0x7fffu + ((u >> 16) & 1u);            // round-to-nearest-even
  return (unsigned short)(u >> 16);
}

__device__ __forceinline__ void gl16(const void* g, void* l) {
  __builtin_amdgcn_global_load_lds((const AS1 unsigned int*)g,
                                   (AS3 unsigned int*)l, 16, 0, 0);
}

__device__ __forceinline__ float sigm(float x) { return 1.0f / (1.0f + __expf(-x)); }

// ---------------------------------------------------------------------------
// prep: dtype conversion + weight re-layout + initial state buffers
// ---------------------------------------------------------------------------
__global__ __launch_bounds__(256, 1) void prep_k(
    const float* __restrict__ Wg,  const float* __restrict__ Wih0,
    const float* __restrict__ Whh0,const float* __restrict__ Wih1,
    const float* __restrict__ Whh1,const float* __restrict__ bih0,
    const float* __restrict__ bhh0,const float* __restrict__ bih1,
    const float* __restrict__ bhh1,const float* __restrict__ h0,
    const float* __restrict__ pout,
    unsigned short* __restrict__ WgBf, unsigned short* __restrict__ W0e,
    unsigned short* __restrict__ Wr0p, unsigned short* __restrict__ Wr1p,
    float* __restrict__ b1p, float* __restrict__ bias0c,
    float* __restrict__ wcd, unsigned short* __restrict__ H0X,
    unsigned short* __restrict__ FOUT, unsigned short* __restrict__ H1I)
{
  const long N0 = 16384000L;           // WgBf
  const long N1 = N0 + 1048576L;       // W0e
  const long N2 = N1 + 2097152L;       // Wr0p
  const long N3 = N2 + 2097152L;       // Wr1p
  const long N4 = N3 + 2048L;          // b1p
  const long N5 = N4 + 2048L;          // bias0c
  const long N6 = N5 + 2048L;          // wcd
  const long N7 = N6 + 49152L;         // state inits (3 x 16384)
  for (long i = blockIdx.x * 256L + threadIdx.x; i < N7; i += 256L * gridDim.x) {
    if (i < N0) {
      WgBf[i] = f2bf(Wg[i]);
    } else if (i < N1) {
      long k = i - N0; int g = (int)(k >> 9); int kk = (int)(k & 511);
      W0e[k] = f2bf(Wih0[g * 1025 + kk]);
    } else if (i < N2) {
      long k = i - N1; int gp = (int)(k >> 10); int kk = (int)(k & 1023);
      int j = gp >> 2, gate = gp & 3; int g = gate * 512 + j;
      float v = (kk < 512) ? Whh0[g * 512 + kk] : Wih0[g * 1025 + 513 + (kk - 512)];
      Wr0p[k] = f2bf(v);
    } else if (i < N3) {
      long k = i - N2; int gp = (int)(k >> 10); int kk = (int)(k & 1023);
      int j = gp >> 2, gate = gp & 3; int g = gate * 512 + j;
      float v = (kk < 512) ? Wih1[g * 512 + kk] : Whh1[g * 512 + (kk - 512)];
      Wr1p[k] = f2bf(v);
    } else if (i < N4) {
      int gp = (int)(i - N3); int j = gp >> 2, gate = gp & 3; int g = gate * 512 + j;
      b1p[gp] = bih1[g] + bhh1[g];
    } else if (i < N5) {
      int g = (int)(i - N4); bias0c[g] = bih0[g] + bhh0[g];
    } else if (i < N6) {
      int g = (int)(i - N5); wcd[g] = Wih0[g * 1025 + 512];
    } else {
      long k = i - N6;                 // 0..49151
      int sub = (int)(k >> 14);        // 0=H0X(h0 l0), 1=H1I(h0 l1), 2=FOUT(pout)
      int e = (int)(k & 16383);
      int wgx = e >> 9, b = (e >> 4) & 31, jl = e & 15;
      int j = wgx * 16 + jl;
      float v = (sub == 0) ? h0[b * 512 + j]
              : (sub == 1) ? h0[16384 + b * 512 + j]
                           : pout[b * 512 + j];
      unsigned short* dst = (sub == 0) ? H0X : (sub == 1) ? H1I : FOUT;
      dst[e] = f2bf(v);
    }
  }
}

// ---------------------------------------------------------------------------
// embedding
// ---------------------------------------------------------------------------
__global__ __launch_bounds__(256, 1) void emb_k(
    const int* __restrict__ ids, const float* __restrict__ wemb,
    const float* __restrict__ semb, unsigned short* __restrict__ ebf)
{
  const int tb = blockIdx.x;
  const int id = ids[tb];
  const int sp = (id < 3) ? (id + 1) : 0;
  const float* wr = wemb + (long)id * 512;
  const float* sr = semb + sp * 512;
  for (int i = threadIdx.x; i < 512; i += 256)
    ebf[tb * 512 + i] = f2bf(wr[i] + sr[i]);
}

// ---------------------------------------------------------------------------
// GEMM: D[m][n] = sum_k A[m][k]*B[n][k]  (A [M][512] bf16, B [N][512] bf16)
// EPI==0: P0t path; EPI==1: generator + per-(row, n-tile) (max,sumexp) -> PMS
// ---------------------------------------------------------------------------
template<int EPI>
__global__ __launch_bounds__(256, 1) void gemm_bt(
    const unsigned short* __restrict__ A,
    const unsigned short* __restrict__ B, int N,
    float* __restrict__ C,
    const float* __restrict__ e0, float* __restrict__ e1,
    const float* __restrict__ e2)
{
  __shared__ unsigned short sA[4096];
  __shared__ unsigned short sB[4096];
  __shared__ float pmw[128][2][2];
  const int tid = threadIdx.x;
  const int l = tid & 63, w = tid >> 6;
  const int nb = N >> 7;
  const int bid = blockIdx.x;
  const int bm = bid / nb, bn = bid - bm * nb;

  const int u0 = w * 128 + l;
  const int u1 = u0 + 64;
  const int r0 = u0 >> 2, c0 = (u0 & 3) ^ (r0 & 3);
  const int r1 = u1 >> 2, c1 = (u1 & 3) ^ (r1 & 3);
  const unsigned short* ga0 = A + (long)(bm * 128 + r0) * 512 + c0 * 8;
  const unsigned short* ga1 = A + (long)(bm * 128 + r1) * 512 + c1 * 8;
  const unsigned short* gb0 = B + (long)(bn * 128 + r0) * 512 + c0 * 8;
  const unsigned short* gb1 = B + (long)(bn * 128 + r1) * 512 + c1 * 8;
  unsigned short* la0 = sA + (w * 2 + 0) * 512;
  unsigned short* la1 = sA + (w * 2 + 1) * 512;
  unsigned short* lb0 = sB + (w * 2 + 0) * 512;
  unsigned short* lb1 = sB + (w * 2 + 1) * 512;

  const int fr = l & 15, fc = l >> 4;
  const int wm = w >> 1, wn = w & 1;
  int aoff[4], boff[4];
#pragma unroll
  for (int mi = 0; mi < 4; ++mi) {
    int row = wm * 64 + mi * 16 + fr;
    aoff[mi] = row * 64 + ((fc ^ (row & 3)) * 16);
  }
#pragma unroll
  for (int ni = 0; ni < 4; ++ni) {
    int row = wn * 64 + ni * 16 + fr;
    boff[ni] = row * 64 + ((fc ^ (row & 3)) * 16);
  }

  f32x4 acc[4][4];
#pragma unroll
  for (int i = 0; i < 4; ++i)
#pragma unroll
    for (int jq = 0; jq < 4; ++jq) acc[i][jq] = (f32x4){0.f, 0.f, 0.f, 0.f};

  for (int kt = 0; kt < 16; ++kt) {
    __syncthreads();
    gl16(ga0 + kt * 32, la0);
    gl16(ga1 + kt * 32, la1);
    gl16(gb0 + kt * 32, lb0);
    gl16(gb1 + kt * 32, lb1);
    asm volatile("s_waitcnt vmcnt(0)" ::: "memory");
    __syncthreads();
    bf16x8 av[4], bv[4];
#pragma unroll
    for (int mi = 0; mi < 4; ++mi)
      av[mi] = *(const bf16x8*)((const char*)sA + aoff[mi]);
#pragma unroll
    for (int ni = 0; ni < 4; ++ni)
      bv[ni] = *(const bf16x8*)((const char*)sB + boff[ni]);
#pragma unroll
    for (int mi = 0; mi < 4; ++mi)
#pragma unroll
      for (int ni = 0; ni < 4; ++ni)
        acc[mi][ni] = __builtin_amdgcn_mfma_f32_16x16x32_bf16(av[mi], bv[ni], acc[mi][ni], 0, 0, 0);
  }

  const int mbase = bm * 128 + wm * 64;
  const int nbase = bn * 128 + wn * 64;

  if (EPI == 0) {
#pragma unroll
    for (int mi = 0; mi < 4; ++mi)
#pragma unroll
      for (int ni = 0; ni < 4; ++ni) {
        const int col = nbase + ni * 16 + fr;
#pragma unroll
        for (int r = 0; r < 4; ++r) {
          const int row = mbase + mi * 16 + fc * 4 + r;
          const int gp = ((row & 511) << 2) | (row >> 9);
          float v = acc[mi][ni][r] + e0[row] + e2[col] * e1[row];
          C[(long)gp * N + col] = v;
        }
      }
  } else {
    float m2[4][4], s2[4][4];
#pragma unroll
    for (int mi = 0; mi < 4; ++mi)
#pragma unroll
      for (int r = 0; r < 4; ++r) { m2[mi][r] = -3.0e38f; s2[mi][r] = 0.f; }
#pragma unroll
    for (int mi = 0; mi < 4; ++mi)
#pragma unroll
      for (int ni = 0; ni < 4; ++ni) {
        const int col = nbase + ni * 16 + fr;
        const float bgc = e0[col];
#pragma unroll
        for (int r = 0; r < 4; ++r) {
          float v = acc[mi][ni][r] + bgc;
          acc[mi][ni][r] = v;
          C[(long)(mbase + mi * 16 + fc * 4 + r) * N + col] = v;
          m2[mi][r] = fmaxf(m2[mi][r], v);
        }
      }
#pragma unroll
    for (int mi = 0; mi < 4; ++mi)
#pragma unroll
      for (int r = 0; r < 4; ++r)
#pragma unroll
        for (int s = 1; s < 16; s <<= 1)
          m2[mi][r] = fmaxf(m2[mi][r], __shfl_xor(m2[mi][r], s));
#pragma unroll
    for (int mi = 0; mi < 4; ++mi)
#pragma unroll
      for (int ni = 0; ni < 4; ++ni)
#pragma unroll
        for (int r = 0; r < 4; ++r)
          s2[mi][r] += __expf(acc[mi][ni][r] - m2[mi][r]);
#pragma unroll
    for (int mi = 0; mi < 4; ++mi)
#pragma unroll
      for (int r = 0; r < 4; ++r)
#pragma unroll
        for (int s = 1; s < 16; s <<= 1)
          s2[mi][r] += __shfl_xor(s2[mi][r], s);
    if (fr == 0) {
#pragma unroll
      for (int mi = 0; mi < 4; ++mi)
#pragma unroll
        for (int r = 0; r < 4; ++r) {
          const int rl = wm * 64 + mi * 16 + fc * 4 + r;
          pmw[rl][wn][0] = m2[mi][r];
          pmw[rl][wn][1] = s2[mi][r];
        }
    }
    __syncthreads();
    if (tid < 128) {
      float ma = pmw[tid][0][0], sa = pmw[tid][0][1];
      float mb = pmw[tid][1][0], sb = pmw[tid][1][1];
      float M = fmaxf(ma, mb);
      float S = sa * __expf(ma - M) + sb * __expf(mb - M);
      float2* PMS = (float2*)e1;
      float2 o; o.x = M; o.y = S;
      PMS[(long)(bm * 128 + tid) * nb + bn] = o;
    }
  }
}

// ---------------------------------------------------------------------------
// Persistent sequential LSTM (R5 structure, proven). 32 WGs x 256 thr.
// WG owns gate rows [wg*64, wg*64+64) i.e. j in [wg*16, wg*16+16).
// sx LDS [32 b][1024 cols] persists: cols 0-511 = h0, cols 512-1023 = h1.
// Per phase: pre-poll MFMA on resident half; poll; stage fresh 32KB half;
// MFMA; gates; 1KB exclusive store; drain; flag.
// flagA: t+1 = phase A(t) done. flagB: 1 = init staged, t+2 = B(t) done.
// ---------------------------------------------------------------------------
__global__ __launch_bounds__(256, 1) void lstm_seq(
    const unsigned short* __restrict__ Wr0p,
    const unsigned short* __restrict__ Wr1p,
    const float* __restrict__ P0t, const float* __restrict__ b1p,
    const float* __restrict__ c0in,
    unsigned short* __restrict__ H0X, unsigned short* __restrict__ H1X,
    const unsigned short* __restrict__ FOUT, const unsigned short* __restrict__ H1I,
    unsigned short* __restrict__ outbf, float* __restrict__ outs,
    unsigned int* __restrict__ flagA, unsigned int* __restrict__ flagB)
{
  const int tid = threadIdx.x;
  const int wg = blockIdx.x;            // 32
  const int l = tid & 63, w = tid >> 6;
  const int fr = l & 15, fc = l >> 4;

  __shared__ unsigned short sx[32768];  // 64KB: [32 b][1024 cols], swizzled
  __shared__ float sg[32][65];
  __shared__ unsigned short sh[32][16];

  const int b = tid & 31, jl0 = tid >> 5;       // jl0 0..7; thread owns jl0, jl0+8
  const int sb = l >> 1, sjh = l & 1;           // stage/store lane mapping

  float c0r[2], c1r[2], h0k[2], h1k[2];
#pragma unroll
  for (int jq = 0; jq < 2; ++jq) {
    c0r[jq] = c0in[b * 512 + wg * 16 + jl0 + jq * 8];
    c1r[jq] = c0in[16384 + b * 512 + wg * 16 + jl0 + jq * 8];
    h0k[jq] = 0.f; h1k[jq] = 0.f;
  }

  float b1v[8];
#pragma unroll
  for (int jq = 0; jq < 2; ++jq)
#pragma unroll
    for (int g = 0; g < 4; ++g)
      b1v[jq * 4 + g] = b1p[(wg * 16 + jl0 + jq * 8) * 4 + g];

  // MFMA addressing
  const char* sxb0 = (const char*)sx + fr * 2048;          // b-rows 0-15
  const char* sxb1 = (const char*)sx + (16 + fr) * 2048;   // b-rows 16-31
  const int xr = (fr & 7) << 4;
  const int wrow = (wg * 64 + w * 16 + fr) * 1024 + fc * 8;

  // staging LDS base
  char* const sxw = (char*)sx + sb * 2048;
  const int sswz = (sb & 7) << 4;

#define STAGE2(srcp, half)                                                    \
  do {                                                                        \
    unsigned long long q0[8], q1[8];                                          \
    _Pragma("unroll")                                                         \
    for (int i = 0; i < 8; ++i) {                                             \
      int u = i * 256 + tid;                                                  \
      q0[i] = __hip_atomic_load((const unsigned long long*)(srcp) + u * 2,    \
                                RLX, AGT);                                    \
      q1[i] = __hip_atomic_load((const unsigned long long*)(srcp) + u * 2 + 1,\
                                RLX, AGT);                                    \
    }                                                                         \
    _Pragma("unroll")                                                         \
    for (int i = 0; i < 8; ++i) {                                             \
      int cb = (half) * 1024 + (i * 4 + w) * 32 + sjh * 16;                   \
      u64x2 v; v.x = q0[i]; v.y = q1[i];                                      \
      *(u64x2*)(sxw + (cb ^ sswz)) = v;                                       \
    }                                                                         \
  } while (0)

#define MFMA_HALF(Wp, k0, a0v, a1v)                                           \
  do {                                                                        \
    _Pragma("unroll")                                                         \
    for (int kt = (k0); kt < (k0) + 16; ++kt) {                               \
      bf16x8 bv = *(const bf16x8*)((Wp) + wrow + kt * 32);                    \
      bf16x8 x0 = *(const bf16x8*)(sxb0 + ((kt * 64 + fc * 16) ^ xr));        \
      bf16x8 x1 = *(const bf16x8*)(sxb1 + ((kt * 64 + fc * 16) ^ xr));        \
      a0v = __builtin_amdgcn_mfma_f32_16x16x32_bf16(x0, bv, a0v, 0, 0, 0);    \
      a1v = __builtin_amdgcn_mfma_f32_16x16x32_bf16(x1, bv, a1v, 0, 0, 0);    \
    }                                                                         \
  } while (0)

#define POLL(flags, tgt)                                                      \
  do {                                                                        \
    const unsigned int* fp = (flags) + ((l & 31) << 5);                       \
    for (;;) {                                                                \
      unsigned int f = __hip_atomic_load(fp, RLX, AGT);                       \
      if (__all((int)(f >= (unsigned int)(tgt)))) break;                      \
      __builtin_amdgcn_s_sleep(1);                                            \
    }                                                                         \
    asm volatile("" ::: "memory");                                            \
  } while (0)

  // ---- pre-loop: stage h0 init into cols 0-511, signal init epoch ----
  STAGE2(H0X, 0);
  __syncthreads();
  if (tid == 0)
    __hip_atomic_store(&flagB[wg << 5], 1u, RLX, AGT);

  for (int t = 0; t < 128; ++t) {
    // ================= phase A: layer 0 =================
    float p0v[8];
#pragma unroll
    for (int jq = 0; jq < 2; ++jq)
#pragma unroll
      for (int g = 0; g < 4; ++g)
        p0v[jq * 4 + g] =
            P0t[(long)((wg * 16 + jl0 + jq * 8) * 4 + g) * 4096 + t * 32 + b];

    f32x4 accA0 = (f32x4){0.f, 0.f, 0.f, 0.f};
    f32x4 accA1 = (f32x4){0.f, 0.f, 0.f, 0.f};
    MFMA_HALF(Wr0p, 0, accA0, accA1);      // resident h0(t-1), cols 0-511

    POLL(flagB, t + 1);                    // h1(t-1) ready everywhere (or init)
    if (t == 0) STAGE2(FOUT, 1); else STAGE2(H1X, 1);
    __syncthreads();
    MFMA_HALF(Wr0p, 16, accA0, accA1);     // fresh h1(t-1)/out, cols 512-1023
#pragma unroll
    for (int r = 0; r < 4; ++r) {
      sg[fc * 4 + r][w * 16 + fr] = accA0[r];
      sg[16 + fc * 4 + r][w * 16 + fr] = accA1[r];
    }
    __syncthreads();
#pragma unroll
    for (int jq = 0; jq < 2; ++jq) {
      const int jl = jl0 + jq * 8;
      float gi = sg[b][jl * 4 + 0] + p0v[jq * 4 + 0];
      float gf = sg[b][jl * 4 + 1] + p0v[jq * 4 + 1];
      float gg = sg[b][jl * 4 + 2] + p0v[jq * 4 + 2];
      float go = sg[b][jl * 4 + 3] + p0v[jq * 4 + 3];
      float cn = sigm(gf) * c0r[jq] + sigm(gi) * tanhf(gg);
      float hn = sigm(go) * tanhf(cn);
      c0r[jq] = cn; h0k[jq] = hn;
      sh[b][jl] = f2bf(hn);
    }
    __syncthreads();
    if (w == 0) {
      u64x2 v = *(const u64x2*)&sh[sb][sjh * 8];
      unsigned long long* dst =
          (unsigned long long*)(H0X + wg * 512 + sb * 16 + sjh * 8);
      __hip_atomic_store(dst,     v.x, RLX, AGT);
      __hip_atomic_store(dst + 1, v.y, RLX, AGT);
      asm volatile("s_waitcnt vmcnt(0)" ::: "memory");
      if (tid == 0)
        __hip_atomic_store(&flagA[wg << 5], (unsigned int)(t + 1), RLX, AGT);
    }

    // ================= phase B: layer 1 =================
    f32x4 accB0 = (f32x4){0.f, 0.f, 0.f, 0.f};
    f32x4 accB1 = (f32x4){0.f, 0.f, 0.f, 0.f};
    if (t == 0) {                          // cols 512-1023 hold FOUT; need h1(-1)
      STAGE2(H1I, 1);
      __syncthreads();
    }
    MFMA_HALF(Wr1p, 16, accB0, accB1);     // resident h1(t-1), cols 512-1023

    POLL(flagA, t + 1);                    // h0(t) ready everywhere
    STAGE2(H0X, 0);
    __syncthreads();
    MFMA_HALF(Wr1p, 0, accB0, accB1);      // fresh h0(t), cols 0-511
#pragma unroll
    for (int r = 0; r < 4; ++r) {
      sg[fc * 4 + r][w * 16 + fr] = accB0[r];
      sg[16 + fc * 4 + r][w * 16 + fr] = accB1[r];
    }
    __syncthreads();
#pragma unroll
    for (int jq = 0; jq < 2; ++jq) {
      const int jl = jl0 + jq * 8;
      float gi = sg[b][jl * 4 + 0] + b1v[jq * 4 + 0];
      float gf = sg[b][jl * 4 + 1] + b1v[jq * 4 + 1];
      float gg = sg[b][jl * 4 + 2] + b1v[jq * 4 + 2];
      float go = sg[b][jl * 4 + 3] + b1v[jq * 4 + 3];
      float cn = sigm(gf) * c1r[jq] + sigm(gi) * tanhf(gg);
      float hn = sigm(go) * tanhf(cn);
      c1r[jq] = cn; h1k[jq] = hn;
      sh[b][jl] = f2bf(hn);
    }
    __syncthreads();
    if (w == 0) {
      u64x2 v = *(const u64x2*)&sh[sb][sjh * 8];
      unsigned long long* dst =
          (unsigned long long*)(H1X + wg * 512 + sb * 16 + sjh * 8);
      __hip_atomic_store(dst,     v.x, RLX, AGT);
      __hip_atomic_store(dst + 1, v.y, RLX, AGT);
      asm volatile("s_waitcnt vmcnt(0)" ::: "memory");
      if (tid == 0)
        __hip_atomic_store(&flagB[wg << 5], (unsigned int)(t + 2), RLX, AGT);
    } else if (w == 1) {
      u64x2 v = *(const u64x2*)&sh[sb][sjh * 8];
      *(u64x2*)(outbf + (t * 32 + sb) * 512 + wg * 16 + sjh * 8) = v;
    }
  }
#undef STAGE2
#undef MFMA_HALF
#undef POLL

  // final state outputs
  float* hT = outs + 131072000;
  float* cT = outs + 131072000 + 32768;
  float* oT = outs + 131072000 + 65536;
#pragma unroll
  for (int jq = 0; jq < 2; ++jq) {
    const int j = wg * 16 + jl0 + jq * 8;
    hT[b * 512 + j] = h0k[jq];
    hT[16384 + b * 512 + j] = h1k[jq];
    cT[b * 512 + j] = c0r[jq];
    cT[16384 + b * 512 + j] = c1r[jq];
    oT[b * 512 + j] = h1k[jq];
  }
}

// ---------------------------------------------------------------------------
// lse: reduce 250 per-tile (max,sumexp) partials per row, then subtract
// ---------------------------------------------------------------------------
__global__ __launch_bounds__(256, 1) void lse_fix(float* __restrict__ sc,
                                                  const float2* __restrict__ pms)
{
  const long row = blockIdx.x;
  float4* p4 = (float4*)(sc + row * 32000L);
  const int tid = threadIdx.x;
  float m = -3.0e38f, s = 0.0f;
  if (tid < 250) {
    float2 p = pms[row * 250 + tid];
    m = p.x; s = p.y;
  }
#pragma unroll
  for (int off = 32; off > 0; off >>= 1) {
    float mo = __shfl_down(m, off);
    float so = __shfl_down(s, off);
    float mn = fmaxf(m, mo);
    s = s * __expf(m - mn) + so * __expf(mo - mn);
    m = mn;
  }
  __shared__ float lm[4], ls[4], lse_sh;
  if ((tid & 63) == 0) { lm[tid >> 6] = m; ls[tid >> 6] = s; }
  __syncthreads();
  if (tid == 0) {
    float M = lm[0], S = ls[0];
#pragma unroll
    for (int i = 1; i < 4; ++i) {
      float mn = fmaxf(M, lm[i]);
      S = S * __expf(M - mn) + ls[i] * __expf(lm[i] - mn);
      M = mn;
    }
    lse_sh = M + __logf(S);
  }
  __syncthreads();
  const float lse = lse_sh;
  for (int i = tid; i < 8000; i += 256) {
    float4 v = p4[i];
    v.x -= lse; v.y -= lse; v.z -= lse; v.w -= lse;
    p4[i] = v;
  }
}

// ---------------------------------------------------------------------------
extern "C" void kernel_launch(void* const* d_in, const int* in_sizes, int n_in,
                              void* d_out, int out_size, void* d_ws, size_t ws_size,
                              hipStream_t stream) {
  const int*   ids  = (const int*)d_in[0];
  const float* cd   = (const float*)d_in[1];
  const float* wemb = (const float*)d_in[2];
  const float* semb = (const float*)d_in[3];
  const float* h0   = (const float*)d_in[4];
  const float* c0   = (const float*)d_in[5];
  const float* pout = (const float*)d_in[6];
  const float* Wih0 = (const float*)d_in[7];
  const float* Whh0 = (const float*)d_in[8];
  const float* bih0 = (const float*)d_in[9];
  const float* bhh0 = (const float*)d_in[10];
  const float* Wih1 = (const float*)d_in[11];
  const float* Whh1 = (const float*)d_in[12];
  const float* bih1 = (const float*)d_in[13];
  const float* bhh1 = (const float*)d_in[14];
  const float* Wg   = (const float*)d_in[15];
  const float* bg   = (const float*)d_in[16];
  float* out = (float*)d_out;

  char* ws = (char*)d_ws;
  unsigned short* WgBf   = (unsigned short*)(ws);
  unsigned short* W0e    = (unsigned short*)(ws + 32768000);
  unsigned short* Wr0p   = (unsigned short*)(ws + 34865152);
  unsigned short* Wr1p   = (unsigned short*)(ws + 39059456);
  float*          b1p    = (float*)(ws + 43253760);
  float*          bias0c = (float*)(ws + 43261952);
  float*          wcd    = (float*)(ws + 43270144);
  unsigned short* embbf  = (unsigned short*)(ws + 43278336);
  unsigned short* outbf  = (unsigned short*)(ws + 47472640);
  float*          P0t    = (float*)(ws + 51666944);
  float*          PMS    = (float*)(ws + 51666944);   // aliases P0t (dead then)
  unsigned int*   flagA  = (unsigned int*)(ws + 85221376);
  unsigned int*   flagB  = (unsigned int*)(ws + 85225472);
  unsigned short* H0X    = (unsigned short*)(ws + 85229568);
  unsigned short* H1X    = (unsigned short*)(ws + 85262336);
  unsigned short* FOUT   = (unsigned short*)(ws + 85295104);
  unsigned short* H1I    = (unsigned short*)(ws + 85327872);

  // clear flags every launch (no cross-call state)
  hipMemsetAsync((void*)flagA, 0, 8192, stream);

  prep_k<<<8192, 256, 0, stream>>>(Wg, Wih0, Whh0, Wih1, Whh1,
                                   bih0, bhh0, bih1, bhh1, h0, pout,
                                   WgBf, W0e, Wr0p, Wr1p, b1p, bias0c, wcd,
                                   H0X, FOUT, H1I);

  emb_k<<<4096, 256, 0, stream>>>(ids, wemb, semb, embbf);

  // P0t[perm(g)][tb] = W0e @ emb^T + bias0 + cd*wcd   (M=2048, N=4096)
  gemm_bt<0><<<512, 256, 0, stream>>>(W0e, embbf, 4096, P0t, bias0c, wcd, cd);

  lstm_seq<<<32, 256, 0, stream>>>(Wr0p, Wr1p, P0t, b1p, c0,
                                   H0X, H1X, FOUT, H1I, outbf, out, flagA, flagB);

  // logits[tb][v] = out_all @ Wg^T + bg; partial (max,sumexp) -> PMS
  gemm_bt<1><<<8000, 256, 0, stream>>>(outbf, WgBf, 32000, out, bg, PMS, nullptr);

  lse_fix<<<4096, 256, 0, stream>>>(out, (const float2*)PMS);
}

// Round 11
// 1797.026 us; speedup vs baseline: 1.5507x; 1.0637x over previous
//
#include <hip/hip_runtime.h>
#include <hip/hip_bf16.h>

// RNNDecoder: emb -> 2-layer LSTM (seq over T=128) -> generator + log_softmax
// T=128 B=32 E=512 H=512 G=2048 V=32000
//
// R11: generator fused into the lstm kernel as co-resident blocks.
//  - 256 blocks: [0,32) = R10 lstm workers; [32,256) = generator blocks that
//    self-schedule 8000 (bm,bn) 128x128 tile-jobs in t-major order.
//  - Worker wave-1 sc1-stores its outbf slice, drains, sets flagC[wg]=t+1
//    (off the critical wave-0 exchange path). Generators poll flagC (backoff)
//    then compute logits for 4 finished timesteps; A staged via sc1 loads
//    (intra-kernel cross-XCD), B via global_load_lds (prior-kernel data).
//  - PMS partials live in P0t's DEAD column slab [128*bm, 128*bm+128)
//    (flagC >= 4bm+4 ==> all worker reads of those columns retired; 512B
//    aligned, no line sharing with live columns). No ws growth.
//  - Residency-safe: LDS 75KB -> 2 blocks/CU -> capacity 512 >= 256 grid;
//    workers never wait on generators (no deadlock mode).
//
// ws layout (bytes): as R10 + flagC u32[32*32] @ 85360640 (4KB)

typedef __attribute__((ext_vector_type(8))) short bf16x8;
typedef __attribute__((ext_vector_type(4))) float f32x4;
typedef __attribute__((ext_vector_type(2))) unsigned long long u64x2;

#define AS1 __attribute__((address_space(1)))
#define AS3 __attribute__((address_space(3)))
#define RLX __ATOMIC_RELAXED
#define AGT __HIP_MEMORY_SCOPE_AGENT
#define NGEN 224

__device__ __forceinline__ unsigned short f2bf(float f) {
  unsigned int u = __builtin_bit_cast(unsigned int, f);
  u += 0x7fffu + ((u >> 16) & 1u);            // round-to-nearest-even
  return (unsigned short)(u >> 16);
}

__device__ __forceinline__ void gl16(const void* g, void* l) {
  __builtin_amdgcn_global_load_lds((const AS1 unsigned int*)g,
                                   (AS3 unsigned int*)l, 16, 0, 0);
}

__device__ __forceinline__ float sigm(float x) { return 1.0f / (1.0f + __expf(-x)); }

// ---------------------------------------------------------------------------
// prep: dtype conversion + weight re-layout + initial state buffers
// ---------------------------------------------------------------------------
__global__ __launch_bounds__(256, 1) void prep_k(
    const float* __restrict__ Wg,  const float* __restrict__ Wih0,
    const float* __restrict__ Whh0,const float* __restrict__ Wih1,
    const float* __restrict__ Whh1,const float* __restrict__ bih0,
    const float* __restrict__ bhh0,const float* __restrict__ bih1,
    const float* __restrict__ bhh1,const float* __restrict__ h0,
    const float* __restrict__ pout,
    unsigned short* __restrict__ WgBf, unsigned short* __restrict__ W0e,
    unsigned short* __restrict__ Wr0p, unsigned short* __restrict__ Wr1p,
    float* __restrict__ b1p, float* __restrict__ bias0c,
    float* __restrict__ wcd, unsigned short* __restrict__ H0X,
    unsigned short* __restrict__ FOUT, unsigned short* __restrict__ H1I)
{
  const long N0 = 16384000L;           // WgBf
  const long N1 = N0 + 1048576L;       // W0e
  const long N2 = N1 + 2097152L;       // Wr0p
  const long N3 = N2 + 2097152L;       // Wr1p
  const long N4 = N3 + 2048L;          // b1p
  const long N5 = N4 + 2048L;          // bias0c
  const long N6 = N5 + 2048L;          // wcd
  const long N7 = N6 + 49152L;         // state inits (3 x 16384)
  for (long i = blockIdx.x * 256L + threadIdx.x; i < N7; i += 256L * gridDim.x) {
    if (i < N0) {
      WgBf[i] = f2bf(Wg[i]);
    } else if (i < N1) {
      long k = i - N0; int g = (int)(k >> 9); int kk = (int)(k & 511);
      W0e[k] = f2bf(Wih0[g * 1025 + kk]);
    } else if (i < N2) {
      long k = i - N1; int gp = (int)(k >> 10); int kk = (int)(k & 1023);
      int j = gp >> 2, gate = gp & 3; int g = gate * 512 + j;
      float v = (kk < 512) ? Whh0[g * 512 + kk] : Wih0[g * 1025 + 513 + (kk - 512)];
      Wr0p[k] = f2bf(v);
    } else if (i < N3) {
      long k = i - N2; int gp = (int)(k >> 10); int kk = (int)(k & 1023);
      int j = gp >> 2, gate = gp & 3; int g = gate * 512 + j;
      float v = (kk < 512) ? Wih1[g * 512 + kk] : Whh1[g * 512 + (kk - 512)];
      Wr1p[k] = f2bf(v);
    } else if (i < N4) {
      int gp = (int)(i - N3); int j = gp >> 2, gate = gp & 3; int g = gate * 512 + j;
      b1p[gp] = bih1[g] + bhh1[g];
    } else if (i < N5) {
      int g = (int)(i - N4); bias0c[g] = bih0[g] + bhh0[g];
    } else if (i < N6) {
      int g = (int)(i - N5); wcd[g] = Wih0[g * 1025 + 512];
    } else {
      long k = i - N6;                 // 0..49151
      int sub = (int)(k >> 14);        // 0=H0X(h0 l0), 1=H1I(h0 l1), 2=FOUT(pout)
      int e = (int)(k & 16383);
      int wgx = e >> 9, b = (e >> 4) & 31, jl = e & 15;
      int j = wgx * 16 + jl;
      float v = (sub == 0) ? h0[b * 512 + j]
              : (sub == 1) ? h0[16384 + b * 512 + j]
                           : pout[b * 512 + j];
      unsigned short* dst = (sub == 0) ? H0X : (sub == 1) ? H1I : FOUT;
      dst[e] = f2bf(v);
    }
  }
}

// ---------------------------------------------------------------------------
// embedding
// ---------------------------------------------------------------------------
__global__ __launch_bounds__(256, 1) void emb_k(
    const int* __restrict__ ids, const float* __restrict__ wemb,
    const float* __restrict__ semb, unsigned short* __restrict__ ebf)
{
  const int tb = blockIdx.x;
  const int id = ids[tb];
  const int sp = (id < 3) ? (id + 1) : 0;
  const float* wr = wemb + (long)id * 512;
  const float* sr = semb + sp * 512;
  for (int i = threadIdx.x; i < 512; i += 256)
    ebf[tb * 512 + i] = f2bf(wr[i] + sr[i]);
}

// ---------------------------------------------------------------------------
// GEMM (P0t path only now): D[m][n] = sum_k A[m][k]*B[n][k]
// ---------------------------------------------------------------------------
__global__ __launch_bounds__(256, 1) void gemm_p0(
    const unsigned short* __restrict__ A,
    const unsigned short* __restrict__ B, int N,
    float* __restrict__ C,
    const float* __restrict__ e0, const float* __restrict__ e1,
    const float* __restrict__ e2)
{
  __shared__ unsigned short sA[4096];
  __shared__ unsigned short sB[4096];
  const int tid = threadIdx.x;
  const int l = tid & 63, w = tid >> 6;
  const int nb = N >> 7;
  const int bid = blockIdx.x;
  const int bm = bid / nb, bn = bid - bm * nb;

  const int u0 = w * 128 + l;
  const int u1 = u0 + 64;
  const int r0 = u0 >> 2, c0 = (u0 & 3) ^ (r0 & 3);
  const int r1 = u1 >> 2, c1 = (u1 & 3) ^ (r1 & 3);
  const unsigned short* ga0 = A + (long)(bm * 128 + r0) * 512 + c0 * 8;
  const unsigned short* ga1 = A + (long)(bm * 128 + r1) * 512 + c1 * 8;
  const unsigned short* gb0 = B + (long)(bn * 128 + r0) * 512 + c0 * 8;
  const unsigned short* gb1 = B + (long)(bn * 128 + r1) * 512 + c1 * 8;
  unsigned short* la0 = sA + (w * 2 + 0) * 512;
  unsigned short* la1 = sA + (w * 2 + 1) * 512;
  unsigned short* lb0 = sB + (w * 2 + 0) * 512;
  unsigned short* lb1 = sB + (w * 2 + 1) * 512;

  const int fr = l & 15, fc = l >> 4;
  const int wm = w >> 1, wn = w & 1;
  int aoff[4], boff[4];
#pragma unroll
  for (int mi = 0; mi < 4; ++mi) {
    int row = wm * 64 + mi * 16 + fr;
    aoff[mi] = row * 64 + ((fc ^ (row & 3)) * 16);
  }
#pragma unroll
  for (int ni = 0; ni < 4; ++ni) {
    int row = wn * 64 + ni * 16 + fr;
    boff[ni] = row * 64 + ((fc ^ (row & 3)) * 16);
  }

  f32x4 acc[4][4];
#pragma unroll
  for (int i = 0; i < 4; ++i)
#pragma unroll
    for (int jq = 0; jq < 4; ++jq) acc[i][jq] = (f32x4){0.f, 0.f, 0.f, 0.f};

  for (int kt = 0; kt < 16; ++kt) {
    __syncthreads();
    gl16(ga0 + kt * 32, la0);
    gl16(ga1 + kt * 32, la1);
    gl16(gb0 + kt * 32, lb0);
    gl16(gb1 + kt * 32, lb1);
    asm volatile("s_waitcnt vmcnt(0)" ::: "memory");
    __syncthreads();
    bf16x8 av[4], bv[4];
#pragma unroll
    for (int mi = 0; mi < 4; ++mi)
      av[mi] = *(const bf16x8*)((const char*)sA + aoff[mi]);
#pragma unroll
    for (int ni = 0; ni < 4; ++ni)
      bv[ni] = *(const bf16x8*)((const char*)sB + boff[ni]);
#pragma unroll
    for (int mi = 0; mi < 4; ++mi)
#pragma unroll
      for (int ni = 0; ni < 4; ++ni)
        acc[mi][ni] = __builtin_amdgcn_mfma_f32_16x16x32_bf16(av[mi], bv[ni], acc[mi][ni], 0, 0, 0);
  }

  const int mbase = bm * 128 + wm * 64;
  const int nbase = bn * 128 + wn * 64;
#pragma unroll
  for (int mi = 0; mi < 4; ++mi)
#pragma unroll
    for (int ni = 0; ni < 4; ++ni) {
      const int col = nbase + ni * 16 + fr;
#pragma unroll
      for (int r = 0; r < 4; ++r) {
        const int row = mbase + mi * 16 + fc * 4 + r;
        const int gp = ((row & 511) << 2) | (row >> 9);
        float v = acc[mi][ni][r] + e0[row] + e2[col] * e1[row];
        C[(long)gp * N + col] = v;
      }
    }
}

// ---------------------------------------------------------------------------
// Fused persistent LSTM + generator. 256 blocks x 256 thr.
// Blocks [0,32): R10 lstm workers (proven exchange). Wave-1 additionally
// sc1-stores outbf slice, drains, sets flagC[wg]=t+1.
// Blocks [32,256): generator blocks; jobs j=bm*250+bn (8000) strided by NGEN;
// poll flagC >= 4*bm+4; A (outbf) via sc1 loads + ds_write; B via gl16;
// epilogue: C=logits+bg, per-(row,tile) (max,sumexp) into P0t's dead slab
// [128*bm .. 128*bm+128) columns.
// ---------------------------------------------------------------------------
__global__ __launch_bounds__(256, 1) void lstm_seq(
    const unsigned short* __restrict__ Wr0p,
    const unsigned short* __restrict__ Wr1p,
    float* __restrict__ P0t, const float* __restrict__ b1p,
    const float* __restrict__ c0in,
    unsigned short* __restrict__ H0X, unsigned short* __restrict__ H1X,
    const unsigned short* __restrict__ FOUT, const unsigned short* __restrict__ H1I,
    unsigned short* __restrict__ outbf, float* __restrict__ outs,
    unsigned int* __restrict__ flagA, unsigned int* __restrict__ flagB,
    unsigned int* __restrict__ flagC,
    const unsigned short* __restrict__ WgBf, const float* __restrict__ bg)
{
  const int tid = threadIdx.x;
  __shared__ char smem[75264] __attribute__((aligned(16)));

  if (blockIdx.x < 32) {
    // ====================== LSTM worker (R10, proven) ======================
    unsigned short* sx = (unsigned short*)smem;                  // 64KB
    float (*sg)[65] = (float(*)[65])(smem + 65536);              // 8320B
    unsigned short (*sh)[16] = (unsigned short(*)[16])(smem + 73856); // 1KB

    const int wg = blockIdx.x;
    const int l = tid & 63, w = tid >> 6;
    const int fr = l & 15, fc = l >> 4;
    const int b = tid & 31, jl0 = tid >> 5;
    const int sb = l >> 1, sjh = l & 1;

    float c0r[2], c1r[2], h0k[2], h1k[2];
#pragma unroll
    for (int jq = 0; jq < 2; ++jq) {
      c0r[jq] = c0in[b * 512 + wg * 16 + jl0 + jq * 8];
      c1r[jq] = c0in[16384 + b * 512 + wg * 16 + jl0 + jq * 8];
      h0k[jq] = 0.f; h1k[jq] = 0.f;
    }

    float b1v[8];
#pragma unroll
    for (int jq = 0; jq < 2; ++jq)
#pragma unroll
      for (int g = 0; g < 4; ++g)
        b1v[jq * 4 + g] = b1p[(wg * 16 + jl0 + jq * 8) * 4 + g];

    const char* sxb0 = (const char*)sx + fr * 2048;
    const char* sxb1 = (const char*)sx + (16 + fr) * 2048;
    const int xr = (fr & 7) << 4;
    const int wrow = (wg * 64 + w * 16 + fr) * 1024 + fc * 8;

    char* const sxw = (char*)sx + sb * 2048;
    const int sswz = (sb & 7) << 4;

#define STAGE2(srcp, half)                                                    \
  do {                                                                        \
    unsigned long long q0[8], q1[8];                                          \
    _Pragma("unroll")                                                         \
    for (int i = 0; i < 8; ++i) {                                             \
      int u = i * 256 + tid;                                                  \
      q0[i] = __hip_atomic_load((const unsigned long long*)(srcp) + u * 2,    \
                                RLX, AGT);                                    \
      q1[i] = __hip_atomic_load((const unsigned long long*)(srcp) + u * 2 + 1,\
                                RLX, AGT);                                    \
    }                                                                         \
    _Pragma("unroll")                                                         \
    for (int i = 0; i < 8; ++i) {                                             \
      int cb = (half) * 1024 + (i * 4 + w) * 32 + sjh * 16;                   \
      u64x2 v; v.x = q0[i]; v.y = q1[i];                                      \
      *(u64x2*)(sxw + (cb ^ sswz)) = v;                                       \
    }                                                                         \
  } while (0)

#define MFMA_HALF(Wp, k0, a0v, a1v)                                           \
  do {                                                                        \
    _Pragma("unroll")                                                         \
    for (int kt = (k0); kt < (k0) + 16; ++kt) {                               \
      bf16x8 bv = *(const bf16x8*)((Wp) + wrow + kt * 32);                    \
      bf16x8 x0 = *(const bf16x8*)(sxb0 + ((kt * 64 + fc * 16) ^ xr));        \
      bf16x8 x1 = *(const bf16x8*)(sxb1 + ((kt * 64 + fc * 16) ^ xr));        \
      a0v = __builtin_amdgcn_mfma_f32_16x16x32_bf16(x0, bv, a0v, 0, 0, 0);    \
      a1v = __builtin_amdgcn_mfma_f32_16x16x32_bf16(x1, bv, a1v, 0, 0, 0);    \
    }                                                                         \
  } while (0)

#define POLL(flags, tgt)                                                      \
  do {                                                                        \
    const unsigned int* fp = (flags) + ((l & 31) << 5);                       \
    for (;;) {                                                                \
      unsigned int f = __hip_atomic_load(fp, RLX, AGT);                       \
      if (__all((int)(f >= (unsigned int)(tgt)))) break;                      \
      __builtin_amdgcn_s_sleep(1);                                            \
    }                                                                         \
    asm volatile("" ::: "memory");                                            \
  } while (0)

    STAGE2(H0X, 0);
    __syncthreads();
    if (tid == 0)
      __hip_atomic_store(&flagB[wg << 5], 1u, RLX, AGT);

    for (int t = 0; t < 128; ++t) {
      // ---------------- phase A: layer 0 ----------------
      float p0v[8];
#pragma unroll
      for (int jq = 0; jq < 2; ++jq)
#pragma unroll
        for (int g = 0; g < 4; ++g)
          p0v[jq * 4 + g] =
              P0t[(long)((wg * 16 + jl0 + jq * 8) * 4 + g) * 4096 + t * 32 + b];

      f32x4 accA0 = (f32x4){0.f, 0.f, 0.f, 0.f};
      f32x4 accA1 = (f32x4){0.f, 0.f, 0.f, 0.f};
      MFMA_HALF(Wr0p, 0, accA0, accA1);

      POLL(flagB, t + 1);
      if (t == 0) STAGE2(FOUT, 1); else STAGE2(H1X, 1);
      __syncthreads();
      MFMA_HALF(Wr0p, 16, accA0, accA1);
#pragma unroll
      for (int r = 0; r < 4; ++r) {
        sg[fc * 4 + r][w * 16 + fr] = accA0[r];
        sg[16 + fc * 4 + r][w * 16 + fr] = accA1[r];
      }
      __syncthreads();
#pragma unroll
      for (int jq = 0; jq < 2; ++jq) {
        const int jl = jl0 + jq * 8;
        float gi = sg[b][jl * 4 + 0] + p0v[jq * 4 + 0];
        float gf = sg[b][jl * 4 + 1] + p0v[jq * 4 + 1];
        float gg = sg[b][jl * 4 + 2] + p0v[jq * 4 + 2];
        float go = sg[b][jl * 4 + 3] + p0v[jq * 4 + 3];
        float cn = sigm(gf) * c0r[jq] + sigm(gi) * tanhf(gg);
        float hn = sigm(go) * tanhf(cn);
        c0r[jq] = cn; h0k[jq] = hn;
        sh[b][jl] = f2bf(hn);
      }
      __syncthreads();
      if (w == 0) {
        u64x2 v = *(const u64x2*)&sh[sb][sjh * 8];
        unsigned long long* dst =
            (unsigned long long*)(H0X + wg * 512 + sb * 16 + sjh * 8);
        __hip_atomic_store(dst,     v.x, RLX, AGT);
        __hip_atomic_store(dst + 1, v.y, RLX, AGT);
        asm volatile("s_waitcnt vmcnt(0)" ::: "memory");
        if (tid == 0)
          __hip_atomic_store(&flagA[wg << 5], (unsigned int)(t + 1), RLX, AGT);
      }

      // ---------------- phase B: layer 1 ----------------
      f32x4 accB0 = (f32x4){0.f, 0.f, 0.f, 0.f};
      f32x4 accB1 = (f32x4){0.f, 0.f, 0.f, 0.f};
      if (t == 0) {
        STAGE2(H1I, 1);
        __syncthreads();
      }
      MFMA_HALF(Wr1p, 16, accB0, accB1);

      POLL(flagA, t + 1);
      STAGE2(H0X, 0);
      __syncthreads();
      MFMA_HALF(Wr1p, 0, accB0, accB1);
#pragma unroll
      for (int r = 0; r < 4; ++r) {
        sg[fc * 4 + r][w * 16 + fr] = accB0[r];
        sg[16 + fc * 4 + r][w * 16 + fr] = accB1[r];
      }
      __syncthreads();
#pragma unroll
      for (int jq = 0; jq < 2; ++jq) {
        const int jl = jl0 + jq * 8;
        float gi = sg[b][jl * 4 + 0] + b1v[jq * 4 + 0];
        float gf = sg[b][jl * 4 + 1] + b1v[jq * 4 + 1];
        float gg = sg[b][jl * 4 + 2] + b1v[jq * 4 + 2];
        float go = sg[b][jl * 4 + 3] + b1v[jq * 4 + 3];
        float cn = sigm(gf) * c1r[jq] + sigm(gi) * tanhf(gg);
        float hn = sigm(go) * tanhf(cn);
        c1r[jq] = cn; h1k[jq] = hn;
        sh[b][jl] = f2bf(hn);
      }
      __syncthreads();
      if (w == 0) {
        u64x2 v = *(const u64x2*)&sh[sb][sjh * 8];
        unsigned long long* dst =
            (unsigned long long*)(H1X + wg * 512 + sb * 16 + sjh * 8);
        __hip_atomic_store(dst,     v.x, RLX, AGT);
        __hip_atomic_store(dst + 1, v.y, RLX, AGT);
        asm volatile("s_waitcnt vmcnt(0)" ::: "memory");
        if (tid == 0)
          __hip_atomic_store(&flagB[wg << 5], (unsigned int)(t + 2), RLX, AGT);
      } else if (w == 1) {
        // sc1 outbf store + drain + flagC (off the w0 critical path)
        const unsigned long long* s = (const unsigned long long*)&sh[sb][sjh * 8];
        unsigned long long* dst =
            (unsigned long long*)(outbf + (t * 32 + sb) * 512 + wg * 16 + sjh * 8);
        __hip_atomic_store(dst,     s[0], RLX, AGT);
        __hip_atomic_store(dst + 1, s[1], RLX, AGT);
        asm volatile("s_waitcnt vmcnt(0)" ::: "memory");
        if (l == 0)
          __hip_atomic_store(&flagC[wg << 5], (unsigned int)(t + 1), RLX, AGT);
      }
    }
#undef STAGE2
#undef MFMA_HALF
#undef POLL

    float* hT = outs + 131072000;
    float* cT = outs + 131072000 + 32768;
    float* oT = outs + 131072000 + 65536;
#pragma unroll
    for (int jq = 0; jq < 2; ++jq) {
      const int j = wg * 16 + jl0 + jq * 8;
      hT[b * 512 + j] = h0k[jq];
      hT[16384 + b * 512 + j] = h1k[jq];
      cT[b * 512 + j] = c0r[jq];
      cT[16384 + b * 512 + j] = c1r[jq];
      oT[b * 512 + j] = h1k[jq];
    }
    return;
  }

  // ========================= generator blocks =========================
  {
    unsigned short* sA = (unsigned short*)smem;            // 8KB
    unsigned short* sB = (unsigned short*)(smem + 8192);   // 8KB
    float (*pmw)[2][2] = (float(*)[2][2])(smem + 16384);   // 2KB

    const int g = (int)blockIdx.x - 32;
    const int l = tid & 63, w = tid >> 6;
    const int fr = l & 15, fc = l >> 4;
    const int wm = w >> 1, wn = w & 1;

    const int u0 = w * 128 + l, u1 = u0 + 64;
    const int r0 = u0 >> 2, c0 = (u0 & 3) ^ (r0 & 3);
    const int r1 = u1 >> 2, c1 = (u1 & 3) ^ (r1 & 3);
    unsigned short* lb0 = sB + (w * 2 + 0) * 512;
    unsigned short* lb1 = sB + (w * 2 + 1) * 512;

    int aoff[4], boff[4];
#pragma unroll
    for (int mi = 0; mi < 4; ++mi) {
      int row = wm * 64 + mi * 16 + fr;
      aoff[mi] = row * 64 + ((fc ^ (row & 3)) * 16);
    }
#pragma unroll
    for (int ni = 0; ni < 4; ++ni) {
      int row = wn * 64 + ni * 16 + fr;
      boff[ni] = row * 64 + ((fc ^ (row & 3)) * 16);
    }

    for (int job = g; job < 8000; job += NGEN) {
      const int bm = job / 250, bn = job - bm * 250;

      if (w == 0) {   // poll: timesteps 4bm..4bm+3 finished everywhere
        const unsigned int* fp = flagC + ((l & 31) << 5);
        const unsigned int tgt = (unsigned int)(4 * bm + 4);
        for (;;) {
          unsigned int f = __hip_atomic_load(fp, RLX, AGT);
          if (__all((int)(f >= tgt))) break;
          __builtin_amdgcn_s_sleep(16);
        }
        asm volatile("" ::: "memory");
      }
      __syncthreads();

      const unsigned short* Ab0 = outbf + (long)(bm * 128 + r0) * 512 + c0 * 8;
      const unsigned short* Ab1 = outbf + (long)(bm * 128 + r1) * 512 + c1 * 8;
      const unsigned short* gb0 = WgBf + (long)(bn * 128 + r0) * 512 + c0 * 8;
      const unsigned short* gb1 = WgBf + (long)(bn * 128 + r1) * 512 + c1 * 8;

      f32x4 acc[4][4];
#pragma unroll
      for (int i = 0; i < 4; ++i)
#pragma unroll
        for (int jq = 0; jq < 4; ++jq) acc[i][jq] = (f32x4){0.f, 0.f, 0.f, 0.f};

      for (int kt = 0; kt < 16; ++kt) {
        __syncthreads();
        unsigned long long a0x = __hip_atomic_load((const unsigned long long*)(Ab0 + kt * 32),     RLX, AGT);
        unsigned long long a0y = __hip_atomic_load((const unsigned long long*)(Ab0 + kt * 32) + 1, RLX, AGT);
        unsigned long long a1x = __hip_atomic_load((const unsigned long long*)(Ab1 + kt * 32),     RLX, AGT);
        unsigned long long a1y = __hip_atomic_load((const unsigned long long*)(Ab1 + kt * 32) + 1, RLX, AGT);
        gl16(gb0 + kt * 32, lb0);
        gl16(gb1 + kt * 32, lb1);
        { u64x2 va; va.x = a0x; va.y = a0y; *(u64x2*)((char*)sA + u0 * 16) = va; }
        { u64x2 va; va.x = a1x; va.y = a1y; *(u64x2*)((char*)sA + u1 * 16) = va; }
        asm volatile("s_waitcnt vmcnt(0)" ::: "memory");
        __syncthreads();
        bf16x8 av[4], bv[4];
#pragma unroll
        for (int mi = 0; mi < 4; ++mi)
          av[mi] = *(const bf16x8*)((const char*)sA + aoff[mi]);
#pragma unroll
        for (int ni = 0; ni < 4; ++ni)
          bv[ni] = *(const bf16x8*)((const char*)sB + boff[ni]);
#pragma unroll
        for (int mi = 0; mi < 4; ++mi)
#pragma unroll
          for (int ni = 0; ni < 4; ++ni)
            acc[mi][ni] = __builtin_amdgcn_mfma_f32_16x16x32_bf16(av[mi], bv[ni], acc[mi][ni], 0, 0, 0);
      }

      const int mbase = bm * 128 + wm * 64;
      const int nbase = bn * 128 + wn * 64;
      float m2[4][4], s2[4][4];
#pragma unroll
      for (int mi = 0; mi < 4; ++mi)
#pragma unroll
        for (int r = 0; r < 4; ++r) { m2[mi][r] = -3.0e38f; s2[mi][r] = 0.f; }
#pragma unroll
      for (int mi = 0; mi < 4; ++mi)
#pragma unroll
        for (int ni = 0; ni < 4; ++ni) {
          const int col = nbase + ni * 16 + fr;
          const float bgc = bg[col];
#pragma unroll
          for (int r = 0; r < 4; ++r) {
            float v = acc[mi][ni][r] + bgc;
            acc[mi][ni][r] = v;
            outs[(long)(mbase + mi * 16 + fc * 4 + r) * 32000L + col] = v;
            m2[mi][r] = fmaxf(m2[mi][r], v);
          }
        }
#pragma unroll
      for (int mi = 0; mi < 4; ++mi)
#pragma unroll
        for (int r = 0; r < 4; ++r)
#pragma unroll
          for (int s = 1; s < 16; s <<= 1)
            m2[mi][r] = fmaxf(m2[mi][r], __shfl_xor(m2[mi][r], s));
#pragma unroll
      for (int mi = 0; mi < 4; ++mi)
#pragma unroll
        for (int ni = 0; ni < 4; ++ni)
#pragma unroll
          for (int r = 0; r < 4; ++r)
            s2[mi][r] += __expf(acc[mi][ni][r] - m2[mi][r]);
#pragma unroll
      for (int mi = 0; mi < 4; ++mi)
#pragma unroll
        for (int r = 0; r < 4; ++r)
#pragma unroll
          for (int s = 1; s < 16; s <<= 1)
            s2[mi][r] += __shfl_xor(s2[mi][r], s);
      if (fr == 0) {
#pragma unroll
        for (int mi = 0; mi < 4; ++mi)
#pragma unroll
          for (int r = 0; r < 4; ++r) {
            const int rl = wm * 64 + mi * 16 + fc * 4 + r;
            pmw[rl][wn][0] = m2[mi][r];
            pmw[rl][wn][1] = s2[mi][r];
          }
      }
      __syncthreads();
      if (tid < 128) {
        float ma = pmw[tid][0][0], sa = pmw[tid][0][1];
        float mb = pmw[tid][1][0], sb2 = pmw[tid][1][1];
        float M = fmaxf(ma, mb);
        float S = sa * __expf(ma - M) + sb2 * __expf(mb - M);
        // PMS -> P0t's dead column slab [128*bm, 128*bm+128)
        int q2 = 2 * (tid * 250 + bn);
        float* p = P0t + ((long)(q2 >> 7)) * 4096 + 128L * bm + (q2 & 127);
        p[0] = M; p[1] = S;
      }
      __syncthreads();
    }
  }
}

// ---------------------------------------------------------------------------
// lse: reduce 250 per-tile (max,sumexp) partials (from P0t dead slabs),
// then subtract row LSE in-place
// ---------------------------------------------------------------------------
__global__ __launch_bounds__(256, 1) void lse_fix(float* __restrict__ sc,
                                                  const float* __restrict__ pmsbase)
{
  const long row = blockIdx.x;                 // 0..4095
  const int bm = (int)(row >> 7), rl = (int)(row & 127);
  float4* p4 = (float4*)(sc + row * 32000L);
  const int tid = threadIdx.x;
  float m = -3.0e38f, s = 0.0f;
  if (tid < 250) {
    int q2 = 2 * (rl * 250 + tid);
    const float* p = pmsbase + ((long)(q2 >> 7)) * 4096 + 128L * bm + (q2 & 127);
    m = p[0]; s = p[1];
  }
#pragma unroll
  for (int off = 32; off > 0; off >>= 1) {
    float mo = __shfl_down(m, off);
    float so = __shfl_down(s, off);
    float mn = fmaxf(m, mo);
    s = s * __expf(m - mn) + so * __expf(mo - mn);
    m = mn;
  }
  __shared__ float lm[4], ls[4], lse_sh;
  if ((tid & 63) == 0) { lm[tid >> 6] = m; ls[tid >> 6] = s; }
  __syncthreads();
  if (tid == 0) {
    float M = lm[0], S = ls[0];
#pragma unroll
    for (int i = 1; i < 4; ++i) {
      float mn = fmaxf(M, lm[i]);
      S = S * __expf(M - mn) + ls[i] * __expf(lm[i] - mn);
      M = mn;
    }
    lse_sh = M + __logf(S);
  }
  __syncthreads();
  const float lse = lse_sh;
  for (int i = tid; i < 8000; i += 256) {
    float4 v = p4[i];
    v.x -= lse; v.y -= lse; v.z -= lse; v.w -= lse;
    p4[i] = v;
  }
}

// ---------------------------------------------------------------------------
extern "C" void kernel_launch(void* const* d_in, const int* in_sizes, int n_in,
                              void* d_out, int out_size, void* d_ws, size_t ws_size,
                              hipStream_t stream) {
  const int*   ids  = (const int*)d_in[0];
  const float* cd   = (const float*)d_in[1];
  const float* wemb = (const float*)d_in[2];
  const float* semb = (const float*)d_in[3];
  const float* h0   = (const float*)d_in[4];
  const float* c0   = (const float*)d_in[5];
  const float* pout = (const float*)d_in[6];
  const float* Wih0 = (const float*)d_in[7];
  const float* Whh0 = (const float*)d_in[8];
  const float* bih0 = (const float*)d_in[9];
  const float* bhh0 = (const float*)d_in[10];
  const float* Wih1 = (const float*)d_in[11];
  const float* Whh1 = (const float*)d_in[12];
  const float* bih1 = (const float*)d_in[13];
  const float* bhh1 = (const float*)d_in[14];
  const float* Wg   = (const float*)d_in[15];
  const float* bg   = (const float*)d_in[16];
  float* out = (float*)d_out;

  char* ws = (char*)d_ws;
  unsigned short* WgBf   = (unsigned short*)(ws);
  unsigned short* W0e    = (unsigned short*)(ws + 32768000);
  unsigned short* Wr0p   = (unsigned short*)(ws + 34865152);
  unsigned short* Wr1p   = (unsigned short*)(ws + 39059456);
  float*          b1p    = (float*)(ws + 43253760);
  float*          bias0c = (float*)(ws + 43261952);
  float*          wcd    = (float*)(ws + 43270144);
  unsigned short* embbf  = (unsigned short*)(ws + 43278336);
  unsigned short* outbf  = (unsigned short*)(ws + 47472640);
  float*          P0t    = (float*)(ws + 51666944);
  unsigned int*   flagA  = (unsigned int*)(ws + 85221376);
  unsigned int*   flagB  = (unsigned int*)(ws + 85225472);
  unsigned short* H0X    = (unsigned short*)(ws + 85229568);
  unsigned short* H1X    = (unsigned short*)(ws + 85262336);
  unsigned short* FOUT   = (unsigned short*)(ws + 85295104);
  unsigned short* H1I    = (unsigned short*)(ws + 85327872);
  unsigned int*   flagC  = (unsigned int*)(ws + 85360640);

  // clear flags every launch (no cross-call state)
  hipMemsetAsync((void*)flagA, 0, 8192, stream);
  hipMemsetAsync((void*)flagC, 0, 4096, stream);

  prep_k<<<8192, 256, 0, stream>>>(Wg, Wih0, Whh0, Wih1, Whh1,
                                   bih0, bhh0, bih1, bhh1, h0, pout,
                                   WgBf, W0e, Wr0p, Wr1p, b1p, bias0c, wcd,
                                   H0X, FOUT, H1I);

  emb_k<<<4096, 256, 0, stream>>>(ids, wemb, semb, embbf);

  // P0t[perm(g)][tb] = W0e @ emb^T + bias0 + cd*wcd   (M=2048, N=4096)
  gemm_p0<<<512, 256, 0, stream>>>(W0e, embbf, 4096, P0t, bias0c, wcd, cd);

  // fused: lstm (blocks 0-31) + generator GEMM (blocks 32-255)
  lstm_seq<<<32 + NGEN, 256, 0, stream>>>(Wr0p, Wr1p, P0t, b1p, c0,
                                          H0X, H1X, FOUT, H1I, outbf, out,
                                          flagA, flagB, flagC, WgBf, bg);

  lse_fix<<<4096, 256, 0, stream>>>(out, P0t);
}

// Round 12
// 1731.251 us; speedup vs baseline: 1.6096x; 1.0380x over previous
//
#include <hip/hip_runtime.h>
#include <hip/hip_bf16.h>

// RNNDecoder: emb -> 2-layer LSTM (seq over T=128) -> generator + log_softmax
// T=128 B=32 E=512 H=512 G=2048 V=32000
//
// R12: LSE-subtract fused as a third co-resident role.
//  - 256 blocks: [0,32) lstm workers (R10 proven exchange); [32,208)
//    generators; [208,256) subtractors.
//  - Generators: logits + PMS partials via sc1 stores, drain, then
//    fetch_add(cntBM[bm]) (line-padded counter). Subtractors poll
//    cntBM==250, reduce 250 partials (sc1), subtract row LSE in place.
//  - Ordering: stores drained before counter (R5-proven transitive chain);
//    subtractor loads after counter poll. Deadlock-free (sub<-gen<-worker,
//    grid 256 <= residency 512).
//
// ws layout: as R11 + cntBM u32[32*32] @ 85364736 (4KB)

typedef __attribute__((ext_vector_type(8))) short bf16x8;
typedef __attribute__((ext_vector_type(4))) float f32x4;
typedef __attribute__((ext_vector_type(2))) unsigned long long u64x2;

#define AS1 __attribute__((address_space(1)))
#define AS3 __attribute__((address_space(3)))
#define RLX __ATOMIC_RELAXED
#define AGT __HIP_MEMORY_SCOPE_AGENT
#define NGEN 176
#define NSUB 48

__device__ __forceinline__ unsigned short f2bf(float f) {
  unsigned int u = __builtin_bit_cast(unsigned int, f);
  u += 0x7fffu + ((u >> 16) & 1u);            // round-to-nearest-even
  return (unsigned short)(u >> 16);
}

__device__ __forceinline__ void gl16(const void* g, void* l) {
  __builtin_amdgcn_global_load_lds((const AS1 unsigned int*)g,
                                   (AS3 unsigned int*)l, 16, 0, 0);
}

__device__ __forceinline__ float sigm(float x) { return 1.0f / (1.0f + __expf(-x)); }

// ---------------------------------------------------------------------------
// prep: dtype conversion + weight re-layout + initial state buffers
// ---------------------------------------------------------------------------
__global__ __launch_bounds__(256, 1) void prep_k(
    const float* __restrict__ Wg,  const float* __restrict__ Wih0,
    const float* __restrict__ Whh0,const float* __restrict__ Wih1,
    const float* __restrict__ Whh1,const float* __restrict__ bih0,
    const float* __restrict__ bhh0,const float* __restrict__ bih1,
    const float* __restrict__ bhh1,const float* __restrict__ h0,
    const float* __restrict__ pout,
    unsigned short* __restrict__ WgBf, unsigned short* __restrict__ W0e,
    unsigned short* __restrict__ Wr0p, unsigned short* __restrict__ Wr1p,
    float* __restrict__ b1p, float* __restrict__ bias0c,
    float* __restrict__ wcd, unsigned short* __restrict__ H0X,
    unsigned short* __restrict__ FOUT, unsigned short* __restrict__ H1I)
{
  const long N0 = 16384000L;           // WgBf
  const long N1 = N0 + 1048576L;       // W0e
  const long N2 = N1 + 2097152L;       // Wr0p
  const long N3 = N2 + 2097152L;       // Wr1p
  const long N4 = N3 + 2048L;          // b1p
  const long N5 = N4 + 2048L;          // bias0c
  const long N6 = N5 + 2048L;          // wcd
  const long N7 = N6 + 49152L;         // state inits (3 x 16384)
  for (long i = blockIdx.x * 256L + threadIdx.x; i < N7; i += 256L * gridDim.x) {
    if (i < N0) {
      WgBf[i] = f2bf(Wg[i]);
    } else if (i < N1) {
      long k = i - N0; int g = (int)(k >> 9); int kk = (int)(k & 511);
      W0e[k] = f2bf(Wih0[g * 1025 + kk]);
    } else if (i < N2) {
      long k = i - N1; int gp = (int)(k >> 10); int kk = (int)(k & 1023);
      int j = gp >> 2, gate = gp & 3; int g = gate * 512 + j;
      float v = (kk < 512) ? Whh0[g * 512 + kk] : Wih0[g * 1025 + 513 + (kk - 512)];
      Wr0p[k] = f2bf(v);
    } else if (i < N3) {
      long k = i - N2; int gp = (int)(k >> 10); int kk = (int)(k & 1023);
      int j = gp >> 2, gate = gp & 3; int g = gate * 512 + j;
      float v = (kk < 512) ? Wih1[g * 512 + kk] : Whh1[g * 512 + (kk - 512)];
      Wr1p[k] = f2bf(v);
    } else if (i < N4) {
      int gp = (int)(i - N3); int j = gp >> 2, gate = gp & 3; int g = gate * 512 + j;
      b1p[gp] = bih1[g] + bhh1[g];
    } else if (i < N5) {
      int g = (int)(i - N4); bias0c[g] = bih0[g] + bhh0[g];
    } else if (i < N6) {
      int g = (int)(i - N5); wcd[g] = Wih0[g * 1025 + 512];
    } else {
      long k = i - N6;                 // 0..49151
      int sub = (int)(k >> 14);        // 0=H0X(h0 l0), 1=H1I(h0 l1), 2=FOUT(pout)
      int e = (int)(k & 16383);
      int wgx = e >> 9, b = (e >> 4) & 31, jl = e & 15;
      int j = wgx * 16 + jl;
      float v = (sub == 0) ? h0[b * 512 + j]
              : (sub == 1) ? h0[16384 + b * 512 + j]
                           : pout[b * 512 + j];
      unsigned short* dst = (sub == 0) ? H0X : (sub == 1) ? H1I : FOUT;
      dst[e] = f2bf(v);
    }
  }
}

// ---------------------------------------------------------------------------
// embedding
// ---------------------------------------------------------------------------
__global__ __launch_bounds__(256, 1) void emb_k(
    const int* __restrict__ ids, const float* __restrict__ wemb,
    const float* __restrict__ semb, unsigned short* __restrict__ ebf)
{
  const int tb = blockIdx.x;
  const int id = ids[tb];
  const int sp = (id < 3) ? (id + 1) : 0;
  const float* wr = wemb + (long)id * 512;
  const float* sr = semb + sp * 512;
  for (int i = threadIdx.x; i < 512; i += 256)
    ebf[tb * 512 + i] = f2bf(wr[i] + sr[i]);
}

// ---------------------------------------------------------------------------
// GEMM (P0t path): D[m][n] = sum_k A[m][k]*B[n][k]
// ---------------------------------------------------------------------------
__global__ __launch_bounds__(256, 1) void gemm_p0(
    const unsigned short* __restrict__ A,
    const unsigned short* __restrict__ B, int N,
    float* __restrict__ C,
    const float* __restrict__ e0, const float* __restrict__ e1,
    const float* __restrict__ e2)
{
  __shared__ unsigned short sA[4096];
  __shared__ unsigned short sB[4096];
  const int tid = threadIdx.x;
  const int l = tid & 63, w = tid >> 6;
  const int nb = N >> 7;
  const int bid = blockIdx.x;
  const int bm = bid / nb, bn = bid - bm * nb;

  const int u0 = w * 128 + l;
  const int u1 = u0 + 64;
  const int r0 = u0 >> 2, c0 = (u0 & 3) ^ (r0 & 3);
  const int r1 = u1 >> 2, c1 = (u1 & 3) ^ (r1 & 3);
  const unsigned short* ga0 = A + (long)(bm * 128 + r0) * 512 + c0 * 8;
  const unsigned short* ga1 = A + (long)(bm * 128 + r1) * 512 + c1 * 8;
  const unsigned short* gb0 = B + (long)(bn * 128 + r0) * 512 + c0 * 8;
  const unsigned short* gb1 = B + (long)(bn * 128 + r1) * 512 + c1 * 8;
  unsigned short* la0 = sA + (w * 2 + 0) * 512;
  unsigned short* la1 = sA + (w * 2 + 1) * 512;
  unsigned short* lb0 = sB + (w * 2 + 0) * 512;
  unsigned short* lb1 = sB + (w * 2 + 1) * 512;

  const int fr = l & 15, fc = l >> 4;
  const int wm = w >> 1, wn = w & 1;
  int aoff[4], boff[4];
#pragma unroll
  for (int mi = 0; mi < 4; ++mi) {
    int row = wm * 64 + mi * 16 + fr;
    aoff[mi] = row * 64 + ((fc ^ (row & 3)) * 16);
  }
#pragma unroll
  for (int ni = 0; ni < 4; ++ni) {
    int row = wn * 64 + ni * 16 + fr;
    boff[ni] = row * 64 + ((fc ^ (row & 3)) * 16);
  }

  f32x4 acc[4][4];
#pragma unroll
  for (int i = 0; i < 4; ++i)
#pragma unroll
    for (int jq = 0; jq < 4; ++jq) acc[i][jq] = (f32x4){0.f, 0.f, 0.f, 0.f};

  for (int kt = 0; kt < 16; ++kt) {
    __syncthreads();
    gl16(ga0 + kt * 32, la0);
    gl16(ga1 + kt * 32, la1);
    gl16(gb0 + kt * 32, lb0);
    gl16(gb1 + kt * 32, lb1);
    asm volatile("s_waitcnt vmcnt(0)" ::: "memory");
    __syncthreads();
    bf16x8 av[4], bv[4];
#pragma unroll
    for (int mi = 0; mi < 4; ++mi)
      av[mi] = *(const bf16x8*)((const char*)sA + aoff[mi]);
#pragma unroll
    for (int ni = 0; ni < 4; ++ni)
      bv[ni] = *(const bf16x8*)((const char*)sB + boff[ni]);
#pragma unroll
    for (int mi = 0; mi < 4; ++mi)
#pragma unroll
      for (int ni = 0; ni < 4; ++ni)
        acc[mi][ni] = __builtin_amdgcn_mfma_f32_16x16x32_bf16(av[mi], bv[ni], acc[mi][ni], 0, 0, 0);
  }

  const int mbase = bm * 128 + wm * 64;
  const int nbase = bn * 128 + wn * 64;
#pragma unroll
  for (int mi = 0; mi < 4; ++mi)
#pragma unroll
    for (int ni = 0; ni < 4; ++ni) {
      const int col = nbase + ni * 16 + fr;
#pragma unroll
      for (int r = 0; r < 4; ++r) {
        const int row = mbase + mi * 16 + fc * 4 + r;
        const int gp = ((row & 511) << 2) | (row >> 9);
        float v = acc[mi][ni][r] + e0[row] + e2[col] * e1[row];
        C[(long)gp * N + col] = v;
      }
    }
}

// ---------------------------------------------------------------------------
// Fused persistent LSTM + generator + LSE-subtract. 256 blocks x 256 thr.
// ---------------------------------------------------------------------------
__global__ __launch_bounds__(256, 1) void lstm_seq(
    const unsigned short* __restrict__ Wr0p,
    const unsigned short* __restrict__ Wr1p,
    float* __restrict__ P0t, const float* __restrict__ b1p,
    const float* __restrict__ c0in,
    unsigned short* __restrict__ H0X, unsigned short* __restrict__ H1X,
    const unsigned short* __restrict__ FOUT, const unsigned short* __restrict__ H1I,
    unsigned short* __restrict__ outbf, float* __restrict__ outs,
    unsigned int* __restrict__ flagA, unsigned int* __restrict__ flagB,
    unsigned int* __restrict__ flagC, unsigned int* __restrict__ cntBM,
    const unsigned short* __restrict__ WgBf, const float* __restrict__ bg)
{
  const int tid = threadIdx.x;
  __shared__ char smem[75264] __attribute__((aligned(16)));

  if (blockIdx.x < 32) {
    // ====================== LSTM worker (R10, proven) ======================
    unsigned short* sx = (unsigned short*)smem;                  // 64KB
    float (*sg)[65] = (float(*)[65])(smem + 65536);              // 8320B
    unsigned short (*sh)[16] = (unsigned short(*)[16])(smem + 73856); // 1KB

    const int wg = blockIdx.x;
    const int l = tid & 63, w = tid >> 6;
    const int fr = l & 15, fc = l >> 4;
    const int b = tid & 31, jl0 = tid >> 5;
    const int sb = l >> 1, sjh = l & 1;

    float c0r[2], c1r[2], h0k[2], h1k[2];
#pragma unroll
    for (int jq = 0; jq < 2; ++jq) {
      c0r[jq] = c0in[b * 512 + wg * 16 + jl0 + jq * 8];
      c1r[jq] = c0in[16384 + b * 512 + wg * 16 + jl0 + jq * 8];
      h0k[jq] = 0.f; h1k[jq] = 0.f;
    }

    float b1v[8];
#pragma unroll
    for (int jq = 0; jq < 2; ++jq)
#pragma unroll
      for (int g = 0; g < 4; ++g)
        b1v[jq * 4 + g] = b1p[(wg * 16 + jl0 + jq * 8) * 4 + g];

    const char* sxb0 = (const char*)sx + fr * 2048;
    const char* sxb1 = (const char*)sx + (16 + fr) * 2048;
    const int xr = (fr & 7) << 4;
    const int wrow = (wg * 64 + w * 16 + fr) * 1024 + fc * 8;

    char* const sxw = (char*)sx + sb * 2048;
    const int sswz = (sb & 7) << 4;

#define STAGE2(srcp, half)                                                    \
  do {                                                                        \
    unsigned long long q0[8], q1[8];                                          \
    _Pragma("unroll")                                                         \
    for (int i = 0; i < 8; ++i) {                                             \
      int u = i * 256 + tid;                                                  \
      q0[i] = __hip_atomic_load((const unsigned long long*)(srcp) + u * 2,    \
                                RLX, AGT);                                    \
      q1[i] = __hip_atomic_load((const unsigned long long*)(srcp) + u * 2 + 1,\
                                RLX, AGT);                                    \
    }                                                                         \
    _Pragma("unroll")                                                         \
    for (int i = 0; i < 8; ++i) {                                             \
      int cb = (half) * 1024 + (i * 4 + w) * 32 + sjh * 16;                   \
      u64x2 v; v.x = q0[i]; v.y = q1[i];                                      \
      *(u64x2*)(sxw + (cb ^ sswz)) = v;                                       \
    }                                                                         \
  } while (0)

#define MFMA_HALF(Wp, k0, a0v, a1v)                                           \
  do {                                                                        \
    _Pragma("unroll")                                                         \
    for (int kt = (k0); kt < (k0) + 16; ++kt) {                               \
      bf16x8 bv = *(const bf16x8*)((Wp) + wrow + kt * 32);                    \
      bf16x8 x0 = *(const bf16x8*)(sxb0 + ((kt * 64 + fc * 16) ^ xr));        \
      bf16x8 x1 = *(const bf16x8*)(sxb1 + ((kt * 64 + fc * 16) ^ xr));        \
      a0v = __builtin_amdgcn_mfma_f32_16x16x32_bf16(x0, bv, a0v, 0, 0, 0);    \
      a1v = __builtin_amdgcn_mfma_f32_16x16x32_bf16(x1, bv, a1v, 0, 0, 0);    \
    }                                                                         \
  } while (0)

#define POLL(flags, tgt)                                                      \
  do {                                                                        \
    const unsigned int* fp = (flags) + ((l & 31) << 5);                       \
    for (;;) {                                                                \
      unsigned int f = __hip_atomic_load(fp, RLX, AGT);                       \
      if (__all((int)(f >= (unsigned int)(tgt)))) break;                      \
      __builtin_amdgcn_s_sleep(1);                                            \
    }                                                                         \
    asm volatile("" ::: "memory");                                            \
  } while (0)

    STAGE2(H0X, 0);
    __syncthreads();
    if (tid == 0)
      __hip_atomic_store(&flagB[wg << 5], 1u, RLX, AGT);

    for (int t = 0; t < 128; ++t) {
      // ---------------- phase A: layer 0 ----------------
      float p0v[8];
#pragma unroll
      for (int jq = 0; jq < 2; ++jq)
#pragma unroll
        for (int g = 0; g < 4; ++g)
          p0v[jq * 4 + g] =
              P0t[(long)((wg * 16 + jl0 + jq * 8) * 4 + g) * 4096 + t * 32 + b];

      f32x4 accA0 = (f32x4){0.f, 0.f, 0.f, 0.f};
      f32x4 accA1 = (f32x4){0.f, 0.f, 0.f, 0.f};
      MFMA_HALF(Wr0p, 0, accA0, accA1);

      POLL(flagB, t + 1);
      if (t == 0) STAGE2(FOUT, 1); else STAGE2(H1X, 1);
      __syncthreads();
      MFMA_HALF(Wr0p, 16, accA0, accA1);
#pragma unroll
      for (int r = 0; r < 4; ++r) {
        sg[fc * 4 + r][w * 16 + fr] = accA0[r];
        sg[16 + fc * 4 + r][w * 16 + fr] = accA1[r];
      }
      __syncthreads();
#pragma unroll
      for (int jq = 0; jq < 2; ++jq) {
        const int jl = jl0 + jq * 8;
        float gi = sg[b][jl * 4 + 0] + p0v[jq * 4 + 0];
        float gf = sg[b][jl * 4 + 1] + p0v[jq * 4 + 1];
        float gg = sg[b][jl * 4 + 2] + p0v[jq * 4 + 2];
        float go = sg[b][jl * 4 + 3] + p0v[jq * 4 + 3];
        float cn = sigm(gf) * c0r[jq] + sigm(gi) * tanhf(gg);
        float hn = sigm(go) * tanhf(cn);
        c0r[jq] = cn; h0k[jq] = hn;
        sh[b][jl] = f2bf(hn);
      }
      __syncthreads();
      if (w == 0) {
        u64x2 v = *(const u64x2*)&sh[sb][sjh * 8];
        unsigned long long* dst =
            (unsigned long long*)(H0X + wg * 512 + sb * 16 + sjh * 8);
        __hip_atomic_store(dst,     v.x, RLX, AGT);
        __hip_atomic_store(dst + 1, v.y, RLX, AGT);
        asm volatile("s_waitcnt vmcnt(0)" ::: "memory");
        if (tid == 0)
          __hip_atomic_store(&flagA[wg << 5], (unsigned int)(t + 1), RLX, AGT);
      }

      // ---------------- phase B: layer 1 ----------------
      f32x4 accB0 = (f32x4){0.f, 0.f, 0.f, 0.f};
      f32x4 accB1 = (f32x4){0.f, 0.f, 0.f, 0.f};
      if (t == 0) {
        STAGE2(H1I, 1);
        __syncthreads();
      }
      MFMA_HALF(Wr1p, 16, accB0, accB1);

      POLL(flagA, t + 1);
      STAGE2(H0X, 0);
      __syncthreads();
      MFMA_HALF(Wr1p, 0, accB0, accB1);
#pragma unroll
      for (int r = 0; r < 4; ++r) {
        sg[fc * 4 + r][w * 16 + fr] = accB0[r];
        sg[16 + fc * 4 + r][w * 16 + fr] = accB1[r];
      }
      __syncthreads();
#pragma unroll
      for (int jq = 0; jq < 2; ++jq) {
        const int jl = jl0 + jq * 8;
        float gi = sg[b][jl * 4 + 0] + b1v[jq * 4 + 0];
        float gf = sg[b][jl * 4 + 1] + b1v[jq * 4 + 1];
        float gg = sg[b][jl * 4 + 2] + b1v[jq * 4 + 2];
        float go = sg[b][jl * 4 + 3] + b1v[jq * 4 + 3];
        float cn = sigm(gf) * c1r[jq] + sigm(gi) * tanhf(gg);
        float hn = sigm(go) * tanhf(cn);
        c1r[jq] = cn; h1k[jq] = hn;
        sh[b][jl] = f2bf(hn);
      }
      __syncthreads();
      if (w == 0) {
        u64x2 v = *(const u64x2*)&sh[sb][sjh * 8];
        unsigned long long* dst =
            (unsigned long long*)(H1X + wg * 512 + sb * 16 + sjh * 8);
        __hip_atomic_store(dst,     v.x, RLX, AGT);
        __hip_atomic_store(dst + 1, v.y, RLX, AGT);
        asm volatile("s_waitcnt vmcnt(0)" ::: "memory");
        if (tid == 0)
          __hip_atomic_store(&flagB[wg << 5], (unsigned int)(t + 2), RLX, AGT);
      } else if (w == 1) {
        const unsigned long long* s = (const unsigned long long*)&sh[sb][sjh * 8];
        unsigned long long* dst =
            (unsigned long long*)(outbf + (t * 32 + sb) * 512 + wg * 16 + sjh * 8);
        __hip_atomic_store(dst,     s[0], RLX, AGT);
        __hip_atomic_store(dst + 1, s[1], RLX, AGT);
        asm volatile("s_waitcnt vmcnt(0)" ::: "memory");
        if (l == 0)
          __hip_atomic_store(&flagC[wg << 5], (unsigned int)(t + 1), RLX, AGT);
      }
    }
#undef STAGE2
#undef MFMA_HALF
#undef POLL

    float* hT = outs + 131072000;
    float* cT = outs + 131072000 + 32768;
    float* oT = outs + 131072000 + 65536;
#pragma unroll
    for (int jq = 0; jq < 2; ++jq) {
      const int j = wg * 16 + jl0 + jq * 8;
      hT[b * 512 + j] = h0k[jq];
      hT[16384 + b * 512 + j] = h1k[jq];
      cT[b * 512 + j] = c0r[jq];
      cT[16384 + b * 512 + j] = c1r[jq];
      oT[b * 512 + j] = h1k[jq];
    }
    return;
  }

  if (blockIdx.x < 32 + NGEN) {
    // ========================= generator blocks =========================
    unsigned short* sA = (unsigned short*)smem;            // 8KB
    unsigned short* sB = (unsigned short*)(smem + 8192);   // 8KB
    float (*pmw)[2][2] = (float(*)[2][2])(smem + 16384);   // 2KB

    const int g = (int)blockIdx.x - 32;
    const int l = tid & 63, w = tid >> 6;
    const int fr = l & 15, fc = l >> 4;
    const int wm = w >> 1, wn = w & 1;

    const int u0 = w * 128 + l, u1 = u0 + 64;
    const int r0 = u0 >> 2, c0 = (u0 & 3) ^ (r0 & 3);
    const int r1 = u1 >> 2, c1 = (u1 & 3) ^ (r1 & 3);
    unsigned short* lb0 = sB + (w * 2 + 0) * 512;
    unsigned short* lb1 = sB + (w * 2 + 1) * 512;

    int aoff[4], boff[4];
#pragma unroll
    for (int mi = 0; mi < 4; ++mi) {
      int row = wm * 64 + mi * 16 + fr;
      aoff[mi] = row * 64 + ((fc ^ (row & 3)) * 16);
    }
#pragma unroll
    for (int ni = 0; ni < 4; ++ni) {
      int row = wn * 64 + ni * 16 + fr;
      boff[ni] = row * 64 + ((fc ^ (row & 3)) * 16);
    }

    for (int job = g; job < 8000; job += NGEN) {
      const int bm = job / 250, bn = job - bm * 250;

      if (w == 0) {   // poll: timesteps 4bm..4bm+3 finished everywhere
        const unsigned int* fp = flagC + ((l & 31) << 5);
        const unsigned int tgt = (unsigned int)(4 * bm + 4);
        for (;;) {
          unsigned int f = __hip_atomic_load(fp, RLX, AGT);
          if (__all((int)(f >= tgt))) break;
          __builtin_amdgcn_s_sleep(16);
        }
        asm volatile("" ::: "memory");
      }
      __syncthreads();

      const unsigned short* Ab0 = outbf + (long)(bm * 128 + r0) * 512 + c0 * 8;
      const unsigned short* Ab1 = outbf + (long)(bm * 128 + r1) * 512 + c1 * 8;
      const unsigned short* gb0 = WgBf + (long)(bn * 128 + r0) * 512 + c0 * 8;
      const unsigned short* gb1 = WgBf + (long)(bn * 128 + r1) * 512 + c1 * 8;

      f32x4 acc[4][4];
#pragma unroll
      for (int i = 0; i < 4; ++i)
#pragma unroll
        for (int jq = 0; jq < 4; ++jq) acc[i][jq] = (f32x4){0.f, 0.f, 0.f, 0.f};

      for (int kt = 0; kt < 16; ++kt) {
        __syncthreads();
        unsigned long long a0x = __hip_atomic_load((const unsigned long long*)(Ab0 + kt * 32),     RLX, AGT);
        unsigned long long a0y = __hip_atomic_load((const unsigned long long*)(Ab0 + kt * 32) + 1, RLX, AGT);
        unsigned long long a1x = __hip_atomic_load((const unsigned long long*)(Ab1 + kt * 32),     RLX, AGT);
        unsigned long long a1y = __hip_atomic_load((const unsigned long long*)(Ab1 + kt * 32) + 1, RLX, AGT);
        gl16(gb0 + kt * 32, lb0);
        gl16(gb1 + kt * 32, lb1);
        { u64x2 va; va.x = a0x; va.y = a0y; *(u64x2*)((char*)sA + u0 * 16) = va; }
        { u64x2 va; va.x = a1x; va.y = a1y; *(u64x2*)((char*)sA + u1 * 16) = va; }
        asm volatile("s_waitcnt vmcnt(0)" ::: "memory");
        __syncthreads();
        bf16x8 av[4], bv[4];
#pragma unroll
        for (int mi = 0; mi < 4; ++mi)
          av[mi] = *(const bf16x8*)((const char*)sA + aoff[mi]);
#pragma unroll
        for (int ni = 0; ni < 4; ++ni)
          bv[ni] = *(const bf16x8*)((const char*)sB + boff[ni]);
#pragma unroll
        for (int mi = 0; mi < 4; ++mi)
#pragma unroll
          for (int ni = 0; ni < 4; ++ni)
            acc[mi][ni] = __builtin_amdgcn_mfma_f32_16x16x32_bf16(av[mi], bv[ni], acc[mi][ni], 0, 0, 0);
      }

      const int mbase = bm * 128 + wm * 64;
      const int nbase = bn * 128 + wn * 64;
      float m2[4][4], s2[4][4];
#pragma unroll
      for (int mi = 0; mi < 4; ++mi)
#pragma unroll
        for (int r = 0; r < 4; ++r) { m2[mi][r] = -3.0e38f; s2[mi][r] = 0.f; }
#pragma unroll
      for (int mi = 0; mi < 4; ++mi)
#pragma unroll
        for (int ni = 0; ni < 4; ++ni) {
          const int col = nbase + ni * 16 + fr;
          const float bgc = bg[col];
#pragma unroll
          for (int r = 0; r < 4; ++r) {
            float v = acc[mi][ni][r] + bgc;
            acc[mi][ni][r] = v;
            __hip_atomic_store(&outs[(long)(mbase + mi * 16 + fc * 4 + r) * 32000L + col],
                               v, RLX, AGT);
            m2[mi][r] = fmaxf(m2[mi][r], v);
          }
        }
#pragma unroll
      for (int mi = 0; mi < 4; ++mi)
#pragma unroll
        for (int r = 0; r < 4; ++r)
#pragma unroll
          for (int s = 1; s < 16; s <<= 1)
            m2[mi][r] = fmaxf(m2[mi][r], __shfl_xor(m2[mi][r], s));
#pragma unroll
      for (int mi = 0; mi < 4; ++mi)
#pragma unroll
        for (int ni = 0; ni < 4; ++ni)
#pragma unroll
          for (int r = 0; r < 4; ++r)
            s2[mi][r] += __expf(acc[mi][ni][r] - m2[mi][r]);
#pragma unroll
      for (int mi = 0; mi < 4; ++mi)
#pragma unroll
        for (int r = 0; r < 4; ++r)
#pragma unroll
          for (int s = 1; s < 16; s <<= 1)
            s2[mi][r] += __shfl_xor(s2[mi][r], s);
      if (fr == 0) {
#pragma unroll
        for (int mi = 0; mi < 4; ++mi)
#pragma unroll
          for (int r = 0; r < 4; ++r) {
            const int rl = wm * 64 + mi * 16 + fc * 4 + r;
            pmw[rl][wn][0] = m2[mi][r];
            pmw[rl][wn][1] = s2[mi][r];
          }
      }
      __syncthreads();
      if (tid < 128) {
        float ma = pmw[tid][0][0], sa = pmw[tid][0][1];
        float mb = pmw[tid][1][0], sb2 = pmw[tid][1][1];
        float M = fmaxf(ma, mb);
        float S = sa * __expf(ma - M) + sb2 * __expf(mb - M);
        // PMS -> P0t's dead column slab [128*bm, 128*bm+128)
        int q2 = 2 * (tid * 250 + bn);
        unsigned long long* p = (unsigned long long*)
            (P0t + ((long)(q2 >> 7)) * 4096 + 128L * bm + (q2 & 127));
        float2 o; o.x = M; o.y = S;
        __hip_atomic_store(p, __builtin_bit_cast(unsigned long long, o), RLX, AGT);
      }
      asm volatile("s_waitcnt vmcnt(0)" ::: "memory");
      __syncthreads();
      if (tid == 0)
        __hip_atomic_fetch_add(&cntBM[bm << 5], 1u, RLX, AGT);
      __syncthreads();
    }
    return;
  }

  // ========================= subtractor blocks =========================
  {
    float* red = (float*)smem;     // red[0..3]=lm, red[4..7]=ls, red[8]=lse
    const int s = (int)blockIdx.x - 32 - NGEN;   // 0..NSUB-1

    for (int row = s; row < 4096; row += NSUB) {
      const int bm = row >> 7, rl = row & 127;
      if (tid == 0) {
        for (;;) {
          unsigned c = __hip_atomic_load(&cntBM[bm << 5], RLX, AGT);
          if (c >= 250u) break;
          __builtin_amdgcn_s_sleep(32);
        }
      }
      __syncthreads();
      asm volatile("" ::: "memory");

      float m = -3.0e38f, sm = 0.0f;
      if (tid < 250) {
        int q2 = 2 * (rl * 250 + tid);
        const unsigned long long* pp = (const unsigned long long*)
            (P0t + ((long)(q2 >> 7)) * 4096 + 128L * bm + (q2 & 127));
        unsigned long long q = __hip_atomic_load(pp, RLX, AGT);
        float2 f = __builtin_bit_cast(float2, q);
        m = f.x; sm = f.y;
      }
#pragma unroll
      for (int off = 32; off > 0; off >>= 1) {
        float mo = __shfl_down(m, off);
        float so = __shfl_down(sm, off);
        float mn = fmaxf(m, mo);
        sm = sm * __expf(m - mn) + so * __expf(mo - mn);
        m = mn;
      }
      if ((tid & 63) == 0) { red[tid >> 6] = m; red[4 + (tid >> 6)] = sm; }
      __syncthreads();
      if (tid == 0) {
        float M = red[0], S = red[4];
#pragma unroll
        for (int i = 1; i < 4; ++i) {
          float mn = fmaxf(M, red[i]);
          S = S * __expf(M - mn) + red[4 + i] * __expf(red[i] - mn);
          M = mn;
        }
        red[8] = M + __logf(S);
      }
      __syncthreads();
      const float lse = red[8];

      float* pr = outs + (long)row * 32000L;
#pragma unroll 2
      for (int i = tid; i < 8000; i += 256) {
        const unsigned long long* lp = (const unsigned long long*)(pr + i * 4);
        unsigned long long qa = __hip_atomic_load(lp,     RLX, AGT);
        unsigned long long qb = __hip_atomic_load(lp + 1, RLX, AGT);
        float2 fa = __builtin_bit_cast(float2, qa);
        float2 fb = __builtin_bit_cast(float2, qb);
        float4 v;
        v.x = fa.x - lse; v.y = fa.y - lse; v.z = fb.x - lse; v.w = fb.y - lse;
        *(float4*)(pr + i * 4) = v;
      }
      __syncthreads();
    }
  }
}

// ---------------------------------------------------------------------------
extern "C" void kernel_launch(void* const* d_in, const int* in_sizes, int n_in,
                              void* d_out, int out_size, void* d_ws, size_t ws_size,
                              hipStream_t stream) {
  const int*   ids  = (const int*)d_in[0];
  const float* cd   = (const float*)d_in[1];
  const float* wemb = (const float*)d_in[2];
  const float* semb = (const float*)d_in[3];
  const float* h0   = (const float*)d_in[4];
  const float* c0   = (const float*)d_in[5];
  const float* pout = (const float*)d_in[6];
  const float* Wih0 = (const float*)d_in[7];
  const float* Whh0 = (const float*)d_in[8];
  const float* bih0 = (const float*)d_in[9];
  const float* bhh0 = (const float*)d_in[10];
  const float* Wih1 = (const float*)d_in[11];
  const float* Whh1 = (const float*)d_in[12];
  const float* bih1 = (const float*)d_in[13];
  const float* bhh1 = (const float*)d_in[14];
  const float* Wg   = (const float*)d_in[15];
  const float* bg   = (const float*)d_in[16];
  float* out = (float*)d_out;

  char* ws = (char*)d_ws;
  unsigned short* WgBf   = (unsigned short*)(ws);
  unsigned short* W0e    = (unsigned short*)(ws + 32768000);
  unsigned short* Wr0p   = (unsigned short*)(ws + 34865152);
  unsigned short* Wr1p   = (unsigned short*)(ws + 39059456);
  float*          b1p    = (float*)(ws + 43253760);
  float*          bias0c = (float*)(ws + 43261952);
  float*          wcd    = (float*)(ws + 43270144);
  unsigned short* embbf  = (unsigned short*)(ws + 43278336);
  unsigned short* outbf  = (unsigned short*)(ws + 47472640);
  float*          P0t    = (float*)(ws + 51666944);
  unsigned int*   flagA  = (unsigned int*)(ws + 85221376);
  unsigned int*   flagB  = (unsigned int*)(ws + 85225472);
  unsigned short* H0X    = (unsigned short*)(ws + 85229568);
  unsigned short* H1X    = (unsigned short*)(ws + 85262336);
  unsigned short* FOUT   = (unsigned short*)(ws + 85295104);
  unsigned short* H1I    = (unsigned short*)(ws + 85327872);
  unsigned int*   flagC  = (unsigned int*)(ws + 85360640);
  unsigned int*   cntBM  = (unsigned int*)(ws + 85364736);

  // clear flags + counters every launch (no cross-call state)
  hipMemsetAsync((void*)flagA, 0, 8192, stream);
  hipMemsetAsync((void*)flagC, 0, 8192, stream);

  prep_k<<<8192, 256, 0, stream>>>(Wg, Wih0, Whh0, Wih1, Whh1,
                                   bih0, bhh0, bih1, bhh1, h0, pout,
                                   WgBf, W0e, Wr0p, Wr1p, b1p, bias0c, wcd,
                                   H0X, FOUT, H1I);

  emb_k<<<4096, 256, 0, stream>>>(ids, wemb, semb, embbf);

  // P0t[perm(g)][tb] = W0e @ emb^T + bias0 + cd*wcd   (M=2048, N=4096)
  gemm_p0<<<512, 256, 0, stream>>>(W0e, embbf, 4096, P0t, bias0c, wcd, cd);

  // fused: lstm (0-31) + generator (32-207) + LSE-subtract (208-255)
  lstm_seq<<<32 + NGEN + NSUB, 256, 0, stream>>>(Wr0p, Wr1p, P0t, b1p, c0,
                                                 H0X, H1X, FOUT, H1I, outbf, out,
                                                 flagA, flagB, flagC, cntBM,
                                                 WgBf, bg);
}